// Round 1
// baseline (1031.331 us; speedup 1.0000x reference)
//
#include <hip/hip_runtime.h>
#include <math.h>

#define NN 50000
#define EE 600000
#define DD 128
#define GG 64
#define NCLS 10
#define GROWS 16

// ---------------- CSR build ----------------

__global__ void hist_kernel(const int* __restrict__ dst, int* __restrict__ cnt, int e) {
    int i = blockIdx.x * blockDim.x + threadIdx.x;
    if (i < e) atomicAdd(&cnt[dst[i]], 1);
}

__global__ __launch_bounds__(1024) void scan_kernel(const int* __restrict__ cnt,
                                                    int* __restrict__ indptr,
                                                    int* __restrict__ cursor,
                                                    int n, int total) {
    __shared__ int buf[1024];
    __shared__ int carry;
    int tid = threadIdx.x;
    if (tid == 0) carry = 0;
    __syncthreads();
    for (int base = 0; base < n; base += 1024) {
        int i = base + tid;
        int v = (i < n) ? cnt[i] : 0;
        buf[tid] = v;
        __syncthreads();
        for (int off = 1; off < 1024; off <<= 1) {
            int tmp = (tid >= off) ? buf[tid - off] : 0;
            __syncthreads();
            buf[tid] += tmp;
            __syncthreads();
        }
        int incl = buf[tid];
        int excl = carry + incl - v;
        if (i < n) { indptr[i] = excl; cursor[i] = excl; }
        __syncthreads();
        if (tid == 1023) carry += buf[1023];
        __syncthreads();
    }
    if (tid == 0) indptr[n] = total;
}

__global__ void fill_kernel(const int* __restrict__ src, const int* __restrict__ dst,
                            int* __restrict__ cursor, int* __restrict__ esrc, int e) {
    int i = blockIdx.x * blockDim.x + threadIdx.x;
    if (i < e) {
        int pos = atomicAdd(&cursor[dst[i]], 1);
        esrc[pos] = src[i];
    }
}

// ---------------- fused QKVS GEMM: [N,128] @ 4x[128,128] ----------------

__global__ __launch_bounds__(128) void gemm_qkvs(
    const float* __restrict__ x,
    const float* __restrict__ wq, const float* __restrict__ bq,
    const float* __restrict__ wk, const float* __restrict__ bk,
    const float* __restrict__ wv, const float* __restrict__ bv,
    const float* __restrict__ ws, const float* __restrict__ bs,
    float* __restrict__ q, float* __restrict__ k,
    float* __restrict__ v, float* __restrict__ s) {
    __shared__ float xs[GROWS][DD];
    int t = threadIdx.x;
    int row0 = blockIdx.x * GROWS;
    #pragma unroll
    for (int r = 0; r < GROWS; ++r)
        xs[r][t] = x[(size_t)(row0 + r) * DD + t];
    __syncthreads();

    float aq[GROWS], ak[GROWS], av[GROWS], as_[GROWS];
    #pragma unroll
    for (int r = 0; r < GROWS; ++r) { aq[r] = 0.f; ak[r] = 0.f; av[r] = 0.f; as_[r] = 0.f; }

    for (int kk = 0; kk < DD; kk += 4) {
        float wq0 = wq[(kk + 0) * DD + t], wq1 = wq[(kk + 1) * DD + t];
        float wq2 = wq[(kk + 2) * DD + t], wq3 = wq[(kk + 3) * DD + t];
        float wk0 = wk[(kk + 0) * DD + t], wk1 = wk[(kk + 1) * DD + t];
        float wk2 = wk[(kk + 2) * DD + t], wk3 = wk[(kk + 3) * DD + t];
        float wv0 = wv[(kk + 0) * DD + t], wv1 = wv[(kk + 1) * DD + t];
        float wv2 = wv[(kk + 2) * DD + t], wv3 = wv[(kk + 3) * DD + t];
        float ws0 = ws[(kk + 0) * DD + t], ws1 = ws[(kk + 1) * DD + t];
        float ws2 = ws[(kk + 2) * DD + t], ws3 = ws[(kk + 3) * DD + t];
        #pragma unroll
        for (int r = 0; r < GROWS; ++r) {
            float4 xv = *(const float4*)&xs[r][kk];
            aq[r]  = fmaf(xv.x, wq0, fmaf(xv.y, wq1, fmaf(xv.z, wq2, fmaf(xv.w, wq3, aq[r]))));
            ak[r]  = fmaf(xv.x, wk0, fmaf(xv.y, wk1, fmaf(xv.z, wk2, fmaf(xv.w, wk3, ak[r]))));
            av[r]  = fmaf(xv.x, wv0, fmaf(xv.y, wv1, fmaf(xv.z, wv2, fmaf(xv.w, wv3, av[r]))));
            as_[r] = fmaf(xv.x, ws0, fmaf(xv.y, ws1, fmaf(xv.z, ws2, fmaf(xv.w, ws3, as_[r]))));
        }
    }

    float bqv = bq[t], bkv = bk[t], bvv = bv[t], bsv = bs[t];
    #pragma unroll
    for (int r = 0; r < GROWS; ++r) {
        size_t o = (size_t)(row0 + r) * DD + t;
        q[o] = aq[r] + bqv;
        k[o] = ak[r] + bkv;
        v[o] = av[r] + bvv;
        s[o] = as_[r] + bsv;
    }
}

// ---------------- per-node online-softmax attention ----------------
// one wave (64 lanes) per destination node; lane owns channels {lane, lane+64}

__global__ __launch_bounds__(256) void attn_kernel(
    const float* __restrict__ q, const float* __restrict__ k,
    const float* __restrict__ v, const float* __restrict__ s,
    const int* __restrict__ indptr, const int* __restrict__ esrc,
    float* __restrict__ hout, int n) {
    int wave = (int)((blockIdx.x * blockDim.x + threadIdx.x) >> 6);
    int lane = threadIdx.x & 63;
    if (wave >= n) return;

    const float* qr = q + (size_t)wave * DD;
    float q0 = qr[lane], q1 = qr[lane + 64];
    int beg = indptr[wave], end = indptr[wave + 1];

    float m = -INFINITY, den = 0.f, a0 = 0.f, a1 = 0.f;
    for (int e = beg; e < end; ++e) {
        int sidx = esrc[e];
        const float* kr = k + (size_t)sidx * DD;
        float p = q0 * kr[lane] + q1 * kr[lane + 64];
        p += __shfl_xor(p, 32);
        p += __shfl_xor(p, 16);
        p += __shfl_xor(p, 8);
        p += __shfl_xor(p, 4);
        p += __shfl_xor(p, 2);
        p += __shfl_xor(p, 1);
        float score = p * 0.088388347648318447f;   // 1/sqrt(128)
        float mn = fmaxf(m, score);
        float scale = __expf(m - mn);              // m=-inf first iter -> 0
        float pe = __expf(score - mn);
        const float* vr = v + (size_t)sidx * DD;
        den = den * scale + pe;
        a0 = a0 * scale + pe * vr[lane];
        a1 = a1 * scale + pe * vr[lane + 64];
        m = mn;
    }
    float inv = den > 0.f ? 1.0f / den : 0.f;
    const float* sr = s + (size_t)wave * DD;
    float o0 = fmaxf(fmaf(a0, inv, sr[lane]), 0.f);
    float o1 = fmaxf(fmaf(a1, inv, sr[lane + 64]), 0.f);
    hout[(size_t)wave * DD + lane] = o0;
    hout[(size_t)wave * DD + lane + 64] = o1;
}

// ---------------- global mean pool ----------------

__global__ void pool_kernel(const float* __restrict__ h, const int* __restrict__ batch,
                            float* __restrict__ gsum, float* __restrict__ gcnt, int n) {
    int idx = blockIdx.x * blockDim.x + threadIdx.x;
    if (idx >= n * DD) return;
    int node = idx >> 7, c = idx & 127;
    int g = batch[node];
    atomicAdd(&gsum[g * DD + c], h[idx]);
    if (c == 0) atomicAdd(&gcnt[g], 1.0f);
}

// ---------------- FC + log_softmax, one 64-lane block per graph ----------------

__global__ __launch_bounds__(64) void head_kernel(
    const float* __restrict__ gsum, const float* __restrict__ gcnt,
    const float* __restrict__ wfc, const float* __restrict__ bfc,
    float* __restrict__ out) {
    int g = blockIdx.x;
    int lane = threadIdx.x;
    float cnt = fmaxf(gcnt[g], 1.0f);
    float inv = 1.0f / cnt;
    float p0 = gsum[g * DD + lane] * inv;
    float p1 = gsum[g * DD + lane + 64] * inv;
    __shared__ float logits[NCLS];
    for (int c = 0; c < NCLS; ++c) {
        float partial = p0 * wfc[lane * NCLS + c] + p1 * wfc[(lane + 64) * NCLS + c];
        partial += __shfl_xor(partial, 32);
        partial += __shfl_xor(partial, 16);
        partial += __shfl_xor(partial, 8);
        partial += __shfl_xor(partial, 4);
        partial += __shfl_xor(partial, 2);
        partial += __shfl_xor(partial, 1);
        if (lane == 0) logits[c] = partial + bfc[c];
    }
    __syncthreads();
    if (lane == 0) {
        float mx = logits[0];
        for (int c = 1; c < NCLS; ++c) mx = fmaxf(mx, logits[c]);
        float sum = 0.f;
        for (int c = 0; c < NCLS; ++c) sum += expf(logits[c] - mx);
        float lse = mx + logf(sum);
        for (int c = 0; c < NCLS; ++c) out[g * NCLS + c] = logits[c] - lse;
    }
}

// ---------------- launch ----------------

extern "C" void kernel_launch(void* const* d_in, const int* in_sizes, int n_in,
                              void* d_out, int out_size, void* d_ws, size_t ws_size,
                              hipStream_t stream) {
    const float* x     = (const float*)d_in[0];
    const int*   ei    = (const int*)d_in[1];   // [2,E]: row0=src, row1=dst
    const int*   batch = (const int*)d_in[2];
    const float* Wq = (const float*)d_in[3];
    const float* bq = (const float*)d_in[4];
    const float* Wk = (const float*)d_in[5];
    const float* bk = (const float*)d_in[6];
    const float* Wv = (const float*)d_in[7];
    const float* bv = (const float*)d_in[8];
    const float* Ws = (const float*)d_in[9];
    const float* bs = (const float*)d_in[10];
    const float* Wfc = (const float*)d_in[11];
    const float* bfc = (const float*)d_in[12];
    float* out = (float*)d_out;

    const size_t ND = (size_t)NN * DD;          // 6.4M floats
    float* hbuf = (float*)d_ws;
    float* qb = hbuf + ND;
    float* kb = qb + ND;
    float* vb = kb + ND;
    float* sb = vb + ND;
    int* cnt    = (int*)(sb + ND);
    int* indptr = cnt + NN;
    int* cursor = indptr + NN + 1;
    int* esrc   = cursor + NN;
    float* gsum = (float*)(esrc + EE);
    float* gcnt = gsum + GG * DD;

    const int* src = ei;
    const int* dst = ei + EE;

    hipMemsetAsync(cnt, 0, NN * sizeof(int), stream);
    hipMemsetAsync(gsum, 0, (GG * DD + GG) * sizeof(float), stream);

    // CSR by dst (built once, reused by both layers)
    hist_kernel<<<(EE + 255) / 256, 256, 0, stream>>>(dst, cnt, EE);
    scan_kernel<<<1, 1024, 0, stream>>>(cnt, indptr, cursor, NN, EE);
    fill_kernel<<<(EE + 255) / 256, 256, 0, stream>>>(src, dst, cursor, esrc, EE);

    for (int l = 0; l < 2; ++l) {
        const float* hin = (l == 0) ? x : hbuf;
        size_t wo = (size_t)l * DD * DD;
        size_t bo = (size_t)l * DD;
        gemm_qkvs<<<NN / GROWS, 128, 0, stream>>>(
            hin, Wq + wo, bq + bo, Wk + wo, bk + bo,
            Wv + wo, bv + bo, Ws + wo, bs + bo,
            qb, kb, vb, sb);
        attn_kernel<<<(NN + 3) / 4, 256, 0, stream>>>(
            qb, kb, vb, sb, indptr, esrc, hbuf, NN);
    }

    pool_kernel<<<((size_t)NN * DD + 255) / 256, 256, 0, stream>>>(hbuf, batch, gsum, gcnt, NN);
    head_kernel<<<GG, 64, 0, stream>>>(gsum, gcnt, Wfc, bfc, out);
}

// Round 2
// 617.375 us; speedup vs baseline: 1.6705x; 1.6705x over previous
//
#include <hip/hip_runtime.h>
#include <math.h>

#define NN 50000
#define EE 600000
#define DD 128
#define GG 64
#define NCLS 10
#define GROWS 16
#define PCHUNK 128

// ---------------- CSR build ----------------

__global__ void hist_kernel(const int* __restrict__ dst, int* __restrict__ cnt, int e) {
    int i = blockIdx.x * blockDim.x + threadIdx.x;
    if (i < e) atomicAdd(&cnt[dst[i]], 1);
}

// shuffle-based scan: 3 barriers per 1024-chunk instead of ~20
__global__ __launch_bounds__(1024) void scan_kernel(const int* __restrict__ cnt,
                                                    int* __restrict__ indptr,
                                                    int* __restrict__ cursor,
                                                    int n, int total) {
    __shared__ int wsum[16];
    __shared__ int carry_s;
    int tid = threadIdx.x;
    int lane = tid & 63, wid = tid >> 6;
    if (tid == 0) carry_s = 0;
    __syncthreads();
    for (int base = 0; base < n; base += 1024) {
        int i = base + tid;
        int v = (i < n) ? cnt[i] : 0;
        int x = v;
        #pragma unroll
        for (int off = 1; off < 64; off <<= 1) {
            int y = __shfl_up(x, off);
            if (lane >= off) x += y;
        }
        if (lane == 63) wsum[wid] = x;
        __syncthreads();
        if (wid == 0) {
            int ws = (lane < 16) ? wsum[lane] : 0;
            int xs = ws;
            #pragma unroll
            for (int off = 1; off < 16; off <<= 1) {
                int y = __shfl_up(xs, off);
                if (lane >= off) xs += y;
            }
            if (lane < 16) wsum[lane] = xs - ws;   // exclusive wave prefix
        }
        __syncthreads();
        int excl = carry_s + wsum[wid] + x - v;
        if (i < n) { indptr[i] = excl; cursor[i] = excl; }
        __syncthreads();                            // all reads of carry_s done
        if (tid == 1023) carry_s += wsum[15] + x;   // chunk total
        __syncthreads();
    }
    if (tid == 0) indptr[n] = total;
}

__global__ void fill_kernel(const int* __restrict__ src, const int* __restrict__ dst,
                            int* __restrict__ cursor, int* __restrict__ esrc, int e) {
    int i = blockIdx.x * blockDim.x + threadIdx.x;
    if (i < e) {
        int pos = atomicAdd(&cursor[dst[i]], 1);
        esrc[pos] = src[i];
    }
}

// ---------------- fused QKVS GEMM: [N,128] @ 4x[128,128] ----------------

__global__ __launch_bounds__(128) void gemm_qkvs(
    const float* __restrict__ x,
    const float* __restrict__ wq, const float* __restrict__ bq,
    const float* __restrict__ wk, const float* __restrict__ bk,
    const float* __restrict__ wv, const float* __restrict__ bv,
    const float* __restrict__ ws, const float* __restrict__ bs,
    float* __restrict__ q, float* __restrict__ k,
    float* __restrict__ v, float* __restrict__ s) {
    __shared__ float xs[GROWS][DD];
    int t = threadIdx.x;
    int row0 = blockIdx.x * GROWS;
    #pragma unroll
    for (int r = 0; r < GROWS; ++r)
        xs[r][t] = x[(size_t)(row0 + r) * DD + t];
    __syncthreads();

    float aq[GROWS], ak[GROWS], av[GROWS], as_[GROWS];
    #pragma unroll
    for (int r = 0; r < GROWS; ++r) { aq[r] = 0.f; ak[r] = 0.f; av[r] = 0.f; as_[r] = 0.f; }

    for (int kk = 0; kk < DD; kk += 4) {
        float wq0 = wq[(kk + 0) * DD + t], wq1 = wq[(kk + 1) * DD + t];
        float wq2 = wq[(kk + 2) * DD + t], wq3 = wq[(kk + 3) * DD + t];
        float wk0 = wk[(kk + 0) * DD + t], wk1 = wk[(kk + 1) * DD + t];
        float wk2 = wk[(kk + 2) * DD + t], wk3 = wk[(kk + 3) * DD + t];
        float wv0 = wv[(kk + 0) * DD + t], wv1 = wv[(kk + 1) * DD + t];
        float wv2 = wv[(kk + 2) * DD + t], wv3 = wv[(kk + 3) * DD + t];
        float ws0 = ws[(kk + 0) * DD + t], ws1 = ws[(kk + 1) * DD + t];
        float ws2 = ws[(kk + 2) * DD + t], ws3 = ws[(kk + 3) * DD + t];
        #pragma unroll
        for (int r = 0; r < GROWS; ++r) {
            float4 xv = *(const float4*)&xs[r][kk];
            aq[r]  = fmaf(xv.x, wq0, fmaf(xv.y, wq1, fmaf(xv.z, wq2, fmaf(xv.w, wq3, aq[r]))));
            ak[r]  = fmaf(xv.x, wk0, fmaf(xv.y, wk1, fmaf(xv.z, wk2, fmaf(xv.w, wk3, ak[r]))));
            av[r]  = fmaf(xv.x, wv0, fmaf(xv.y, wv1, fmaf(xv.z, wv2, fmaf(xv.w, wv3, av[r]))));
            as_[r] = fmaf(xv.x, ws0, fmaf(xv.y, ws1, fmaf(xv.z, ws2, fmaf(xv.w, ws3, as_[r]))));
        }
    }

    float bqv = bq[t], bkv = bk[t], bvv = bv[t], bsv = bs[t];
    #pragma unroll
    for (int r = 0; r < GROWS; ++r) {
        size_t o = (size_t)(row0 + r) * DD + t;
        q[o] = aq[r] + bqv;
        k[o] = ak[r] + bkv;
        v[o] = av[r] + bvv;
        s[o] = as_[r] + bsv;
    }
}

// ---------------- per-node online-softmax attention ----------------

__global__ __launch_bounds__(256) void attn_kernel(
    const float* __restrict__ q, const float* __restrict__ k,
    const float* __restrict__ v, const float* __restrict__ s,
    const int* __restrict__ indptr, const int* __restrict__ esrc,
    float* __restrict__ hout, int n) {
    int wave = (int)((blockIdx.x * blockDim.x + threadIdx.x) >> 6);
    int lane = threadIdx.x & 63;
    if (wave >= n) return;

    const float* qr = q + (size_t)wave * DD;
    float q0 = qr[lane], q1 = qr[lane + 64];
    int beg = indptr[wave], end = indptr[wave + 1];

    float m = -INFINITY, den = 0.f, a0 = 0.f, a1 = 0.f;
    for (int e = beg; e < end; ++e) {
        int sidx = esrc[e];
        const float* kr = k + (size_t)sidx * DD;
        float p = q0 * kr[lane] + q1 * kr[lane + 64];
        p += __shfl_xor(p, 32);
        p += __shfl_xor(p, 16);
        p += __shfl_xor(p, 8);
        p += __shfl_xor(p, 4);
        p += __shfl_xor(p, 2);
        p += __shfl_xor(p, 1);
        float score = p * 0.088388347648318447f;   // 1/sqrt(128)
        float mn = fmaxf(m, score);
        float scale = __expf(m - mn);              // m=-inf first iter -> 0
        float pe = __expf(score - mn);
        const float* vr = v + (size_t)sidx * DD;
        den = den * scale + pe;
        a0 = a0 * scale + pe * vr[lane];
        a1 = a1 * scale + pe * vr[lane + 64];
        m = mn;
    }
    float inv = den > 0.f ? 1.0f / den : 0.f;
    const float* sr = s + (size_t)wave * DD;
    float o0 = fmaxf(fmaf(a0, inv, sr[lane]), 0.f);
    float o1 = fmaxf(fmaf(a1, inv, sr[lane + 64]), 0.f);
    hout[(size_t)wave * DD + lane] = o0;
    hout[(size_t)wave * DD + lane + 64] = o1;
}

// ---------------- global mean pool: segmented running sum, few atomics ----------------
// batch is sorted -> contiguous strips; block = 128 channels x 128-node strip.
// Atomics: ~(nblocks + #graph boundaries) * 128 ≈ 58k vs 6.4M before.

__global__ __launch_bounds__(128) void pool_kernel(const float* __restrict__ h,
                                                   const int* __restrict__ batch,
                                                   float* __restrict__ gsum,
                                                   float* __restrict__ gcnt, int n) {
    __shared__ int bsh[PCHUNK];
    int t = threadIdx.x;
    int node0 = blockIdx.x * PCHUNK;
    int nnodes = min(PCHUNK, n - node0);
    if (t < nnodes) bsh[t] = batch[node0 + t];
    __syncthreads();

    int cur = bsh[0];
    float acc = 0.f;
    int cnt = 0;
    int j = 0;
    for (; j + 4 <= nnodes; j += 4) {
        // 4 independent loads in flight
        float v0 = h[(size_t)(node0 + j + 0) * DD + t];
        float v1 = h[(size_t)(node0 + j + 1) * DD + t];
        float v2 = h[(size_t)(node0 + j + 2) * DD + t];
        float v3 = h[(size_t)(node0 + j + 3) * DD + t];
        int g0 = bsh[j + 0], g1 = bsh[j + 1], g2 = bsh[j + 2], g3 = bsh[j + 3];
        #pragma unroll
        for (int u = 0; u < 4; ++u) {
            int g = (u == 0) ? g0 : (u == 1) ? g1 : (u == 2) ? g2 : g3;
            float val = (u == 0) ? v0 : (u == 1) ? v1 : (u == 2) ? v2 : v3;
            if (g != cur) {          // uniform branch across block
                atomicAdd(&gsum[cur * DD + t], acc);
                if (t == 0) atomicAdd(&gcnt[cur], (float)cnt);
                acc = 0.f; cnt = 0; cur = g;
            }
            acc += val; ++cnt;
        }
    }
    for (; j < nnodes; ++j) {
        int g = bsh[j];
        float val = h[(size_t)(node0 + j) * DD + t];
        if (g != cur) {
            atomicAdd(&gsum[cur * DD + t], acc);
            if (t == 0) atomicAdd(&gcnt[cur], (float)cnt);
            acc = 0.f; cnt = 0; cur = g;
        }
        acc += val; ++cnt;
    }
    if (cnt > 0) {
        atomicAdd(&gsum[cur * DD + t], acc);
        if (t == 0) atomicAdd(&gcnt[cur], (float)cnt);
    }
}

// ---------------- FC + log_softmax, one 64-lane block per graph ----------------

__global__ __launch_bounds__(64) void head_kernel(
    const float* __restrict__ gsum, const float* __restrict__ gcnt,
    const float* __restrict__ wfc, const float* __restrict__ bfc,
    float* __restrict__ out) {
    int g = blockIdx.x;
    int lane = threadIdx.x;
    float cnt = fmaxf(gcnt[g], 1.0f);
    float inv = 1.0f / cnt;
    float p0 = gsum[g * DD + lane] * inv;
    float p1 = gsum[g * DD + lane + 64] * inv;
    __shared__ float logits[NCLS];
    for (int c = 0; c < NCLS; ++c) {
        float partial = p0 * wfc[lane * NCLS + c] + p1 * wfc[(lane + 64) * NCLS + c];
        partial += __shfl_xor(partial, 32);
        partial += __shfl_xor(partial, 16);
        partial += __shfl_xor(partial, 8);
        partial += __shfl_xor(partial, 4);
        partial += __shfl_xor(partial, 2);
        partial += __shfl_xor(partial, 1);
        if (lane == 0) logits[c] = partial + bfc[c];
    }
    __syncthreads();
    if (lane == 0) {
        float mx = logits[0];
        for (int c = 1; c < NCLS; ++c) mx = fmaxf(mx, logits[c]);
        float sum = 0.f;
        for (int c = 0; c < NCLS; ++c) sum += expf(logits[c] - mx);
        float lse = mx + logf(sum);
        for (int c = 0; c < NCLS; ++c) out[g * NCLS + c] = logits[c] - lse;
    }
}

// ---------------- launch ----------------

extern "C" void kernel_launch(void* const* d_in, const int* in_sizes, int n_in,
                              void* d_out, int out_size, void* d_ws, size_t ws_size,
                              hipStream_t stream) {
    const float* x     = (const float*)d_in[0];
    const int*   ei    = (const int*)d_in[1];   // [2,E]: row0=src, row1=dst
    const int*   batch = (const int*)d_in[2];
    const float* Wq = (const float*)d_in[3];
    const float* bq = (const float*)d_in[4];
    const float* Wk = (const float*)d_in[5];
    const float* bk = (const float*)d_in[6];
    const float* Wv = (const float*)d_in[7];
    const float* bv = (const float*)d_in[8];
    const float* Ws = (const float*)d_in[9];
    const float* bs = (const float*)d_in[10];
    const float* Wfc = (const float*)d_in[11];
    const float* bfc = (const float*)d_in[12];
    float* out = (float*)d_out;

    const size_t ND = (size_t)NN * DD;
    float* hbuf = (float*)d_ws;
    float* qb = hbuf + ND;
    float* kb = qb + ND;
    float* vb = kb + ND;
    float* sb = vb + ND;
    int* cnt    = (int*)(sb + ND);
    int* indptr = cnt + NN;
    int* cursor = indptr + NN + 1;
    int* esrc   = cursor + NN;
    float* gsum = (float*)(esrc + EE);
    float* gcnt = gsum + GG * DD;

    const int* src = ei;
    const int* dst = ei + EE;

    hipMemsetAsync(cnt, 0, NN * sizeof(int), stream);
    hipMemsetAsync(gsum, 0, (GG * DD + GG) * sizeof(float), stream);

    hist_kernel<<<(EE + 255) / 256, 256, 0, stream>>>(dst, cnt, EE);
    scan_kernel<<<1, 1024, 0, stream>>>(cnt, indptr, cursor, NN, EE);
    fill_kernel<<<(EE + 255) / 256, 256, 0, stream>>>(src, dst, cursor, esrc, EE);

    for (int l = 0; l < 2; ++l) {
        const float* hin = (l == 0) ? x : hbuf;
        size_t wo = (size_t)l * DD * DD;
        size_t bo = (size_t)l * DD;
        gemm_qkvs<<<NN / GROWS, 128, 0, stream>>>(
            hin, Wq + wo, bq + bo, Wk + wo, bk + bo,
            Wv + wo, bv + bo, Ws + wo, bs + bo,
            qb, kb, vb, sb);
        attn_kernel<<<(NN + 3) / 4, 256, 0, stream>>>(
            qb, kb, vb, sb, indptr, esrc, hbuf, NN);
    }

    pool_kernel<<<(NN + PCHUNK - 1) / PCHUNK, 128, 0, stream>>>(hbuf, batch, gsum, gcnt, NN);
    head_kernel<<<GG, 64, 0, stream>>>(gsum, gcnt, Wfc, bfc, out);
}

// Round 3
// 542.393 us; speedup vs baseline: 1.9014x; 1.1382x over previous
//
#include <hip/hip_runtime.h>
#include <math.h>

#define NN 50000
#define EE 600000
#define DD 128
#define GG 64
#define NCLS 10
#define PCHUNK 128

typedef __attribute__((ext_vector_type(8))) __bf16 bf16x8;
typedef __attribute__((ext_vector_type(8))) unsigned short u16x8;
typedef __attribute__((ext_vector_type(4))) float f32x4;

__device__ __forceinline__ unsigned short f2bf(float f) {
    unsigned int u = __float_as_uint(f);
    u += 0x7fff + ((u >> 16) & 1);     // round-to-nearest-even
    return (unsigned short)(u >> 16);
}

// ---------------- CSR build ----------------

__global__ void hist_kernel(const int* __restrict__ dst, int* __restrict__ cnt, int e) {
    int i = blockIdx.x * blockDim.x + threadIdx.x;
    if (i < e) atomicAdd(&cnt[dst[i]], 1);
}

__global__ __launch_bounds__(1024) void scan_kernel(const int* __restrict__ cnt,
                                                    int* __restrict__ indptr,
                                                    int* __restrict__ cursor,
                                                    int n, int total) {
    __shared__ int wsum[16];
    __shared__ int carry_s;
    int tid = threadIdx.x;
    int lane = tid & 63, wid = tid >> 6;
    if (tid == 0) carry_s = 0;
    __syncthreads();
    for (int base = 0; base < n; base += 1024) {
        int i = base + tid;
        int v = (i < n) ? cnt[i] : 0;
        int x = v;
        #pragma unroll
        for (int off = 1; off < 64; off <<= 1) {
            int y = __shfl_up(x, off);
            if (lane >= off) x += y;
        }
        if (lane == 63) wsum[wid] = x;
        __syncthreads();
        if (wid == 0) {
            int ws = (lane < 16) ? wsum[lane] : 0;
            int xs = ws;
            #pragma unroll
            for (int off = 1; off < 16; off <<= 1) {
                int y = __shfl_up(xs, off);
                if (lane >= off) xs += y;
            }
            if (lane < 16) wsum[lane] = xs - ws;
        }
        __syncthreads();
        int excl = carry_s + wsum[wid] + x - v;
        if (i < n) { indptr[i] = excl; cursor[i] = excl; }
        __syncthreads();
        if (tid == 1023) carry_s += wsum[15] + x;
        __syncthreads();
    }
    if (tid == 0) indptr[n] = total;
}

__global__ void fill_kernel(const int* __restrict__ src, const int* __restrict__ dst,
                            int* __restrict__ cursor, int* __restrict__ esrc, int e) {
    int i = blockIdx.x * blockDim.x + threadIdx.x;
    if (i < e) {
        int pos = atomicAdd(&cursor[dst[i]], 1);
        esrc[pos] = src[i];
    }
}

// ---------------- weight pre-transpose + bf16 convert (once) ----------------
// wt[(l*4+m)*16384 + n*128 + k] = bf16(W_m[l][k][n])

__global__ void wt_kernel(const float* __restrict__ wq, const float* __restrict__ wk,
                          const float* __restrict__ wv, const float* __restrict__ ws,
                          unsigned short* __restrict__ wt) {
    int idx = blockIdx.x * 256 + threadIdx.x;       // 0..131071
    int k = idx & 127;
    int n = (idx >> 7) & 127;
    int lm = idx >> 14;                             // l*4+m
    int l = lm >> 2, m = lm & 3;
    const float* w = (m == 0) ? wq : (m == 1) ? wk : (m == 2) ? wv : ws;
    wt[idx] = f2bf(w[l * 16384 + k * 128 + n]);
}

// ---------------- bf16 MFMA QKVS GEMM ----------------
// out[128 rows x 128 cols] per block; blockIdx.y selects matrix (q/k/v/s).
// LDS pitch 136 ushorts (= 17 x 16B): conflict-free for both b128 staging
// writes and fragment reads (8 lanes per 4-bank group).

__global__ __launch_bounds__(256) void gemm_mfma(
    const float* __restrict__ x,
    const unsigned short* __restrict__ wt,      // this layer: [4][128][128] bf16, n-major
    const float* __restrict__ bq, const float* __restrict__ bk,
    const float* __restrict__ bv, const float* __restrict__ bs,
    float* __restrict__ q, float* __restrict__ k,
    float* __restrict__ v, float* __restrict__ s) {
    __shared__ __align__(16) unsigned short As[128 * 136];
    __shared__ __align__(16) unsigned short Bs[128 * 136];

    int t = threadIdx.x;
    int mat = blockIdx.y;
    int row0 = blockIdx.x * 128;

    const unsigned short* wm_ = wt + mat * 16384;
    const float* bias = (mat == 0) ? bq : (mat == 1) ? bk : (mat == 2) ? bv : bs;
    float* out = (mat == 0) ? q : (mat == 1) ? k : (mat == 2) ? v : s;

    int kg = t & 15, rb = t >> 4;
    #pragma unroll
    for (int i = 0; i < 8; ++i) {
        int row = rb + i * 16;
        int grow = row0 + row;
        float4 f0 = {0.f, 0.f, 0.f, 0.f}, f1 = {0.f, 0.f, 0.f, 0.f};
        if (grow < NN) {
            const float* p = x + (size_t)grow * DD + kg * 8;
            f0 = *(const float4*)p;
            f1 = *(const float4*)(p + 4);
        }
        u16x8 a8;
        a8[0] = f2bf(f0.x); a8[1] = f2bf(f0.y); a8[2] = f2bf(f0.z); a8[3] = f2bf(f0.w);
        a8[4] = f2bf(f1.x); a8[5] = f2bf(f1.y); a8[6] = f2bf(f1.z); a8[7] = f2bf(f1.w);
        *(u16x8*)&As[row * 136 + kg * 8] = a8;
        // B: already bf16, n-major -> same fragment pattern as A
        *(u16x8*)&Bs[row * 136 + kg * 8] = *(const u16x8*)(wm_ + row * 128 + kg * 8);
    }
    __syncthreads();

    int lane = t & 63;
    int wave = t >> 6;
    int wm2 = wave >> 1, wn2 = wave & 1;
    int lr = lane & 15, quad = lane >> 4;

    f32x4 acc[4][4];
    #pragma unroll
    for (int a = 0; a < 4; ++a)
        #pragma unroll
        for (int b = 0; b < 4; ++b)
            acc[a][b] = (f32x4){0.f, 0.f, 0.f, 0.f};

    #pragma unroll
    for (int ks = 0; ks < 4; ++ks) {
        bf16x8 af[4], bfr[4];
        #pragma unroll
        for (int tm = 0; tm < 4; ++tm)
            af[tm] = *(const bf16x8*)&As[(wm2 * 64 + tm * 16 + lr) * 136 + ks * 32 + quad * 8];
        #pragma unroll
        for (int tn = 0; tn < 4; ++tn)
            bfr[tn] = *(const bf16x8*)&Bs[(wn2 * 64 + tn * 16 + lr) * 136 + ks * 32 + quad * 8];
        #pragma unroll
        for (int tm = 0; tm < 4; ++tm)
            #pragma unroll
            for (int tn = 0; tn < 4; ++tn)
                acc[tm][tn] = __builtin_amdgcn_mfma_f32_16x16x32_bf16(
                    af[tm], bfr[tn], acc[tm][tn], 0, 0, 0);
    }

    // C/D layout: col = lane&15, row = quad*4 + reg  [measured m89/m91]
    #pragma unroll
    for (int tn = 0; tn < 4; ++tn) {
        int col = wn2 * 64 + tn * 16 + lr;
        float bv_ = bias[col];
        #pragma unroll
        for (int tm = 0; tm < 4; ++tm) {
            int nb = row0 + wm2 * 64 + tm * 16 + quad * 4;
            #pragma unroll
            for (int r = 0; r < 4; ++r) {
                int node = nb + r;
                if (node < NN)
                    out[(size_t)node * DD + col] = acc[tm][tn][r] + bv_;
            }
        }
    }
}

// ---------------- per-node online-softmax attention ----------------

__global__ __launch_bounds__(256) void attn_kernel(
    const float* __restrict__ q, const float* __restrict__ k,
    const float* __restrict__ v, const float* __restrict__ s,
    const int* __restrict__ indptr, const int* __restrict__ esrc,
    float* __restrict__ hout, int n) {
    int wave = (int)((blockIdx.x * blockDim.x + threadIdx.x) >> 6);
    int lane = threadIdx.x & 63;
    if (wave >= n) return;

    const float* qr = q + (size_t)wave * DD;
    float q0 = qr[lane], q1 = qr[lane + 64];
    int beg = indptr[wave], end = indptr[wave + 1];

    float m = -INFINITY, den = 0.f, a0 = 0.f, a1 = 0.f;
    for (int e = beg; e < end; ++e) {
        int sidx = esrc[e];
        const float* kr = k + (size_t)sidx * DD;
        float p = q0 * kr[lane] + q1 * kr[lane + 64];
        p += __shfl_xor(p, 32);
        p += __shfl_xor(p, 16);
        p += __shfl_xor(p, 8);
        p += __shfl_xor(p, 4);
        p += __shfl_xor(p, 2);
        p += __shfl_xor(p, 1);
        float score = p * 0.088388347648318447f;
        float mn = fmaxf(m, score);
        float scale = __expf(m - mn);
        float pe = __expf(score - mn);
        const float* vr = v + (size_t)sidx * DD;
        den = den * scale + pe;
        a0 = a0 * scale + pe * vr[lane];
        a1 = a1 * scale + pe * vr[lane + 64];
        m = mn;
    }
    float inv = den > 0.f ? 1.0f / den : 0.f;
    const float* sr = s + (size_t)wave * DD;
    float o0 = fmaxf(fmaf(a0, inv, sr[lane]), 0.f);
    float o1 = fmaxf(fmaf(a1, inv, sr[lane + 64]), 0.f);
    hout[(size_t)wave * DD + lane] = o0;
    hout[(size_t)wave * DD + lane + 64] = o1;
}

// ---------------- global mean pool: segmented running sum ----------------

__global__ __launch_bounds__(128) void pool_kernel(const float* __restrict__ h,
                                                   const int* __restrict__ batch,
                                                   float* __restrict__ gsum,
                                                   float* __restrict__ gcnt, int n) {
    __shared__ int bsh[PCHUNK];
    int t = threadIdx.x;
    int node0 = blockIdx.x * PCHUNK;
    int nnodes = min(PCHUNK, n - node0);
    if (t < nnodes) bsh[t] = batch[node0 + t];
    __syncthreads();

    int cur = bsh[0];
    float acc = 0.f;
    int cnt = 0;
    int j = 0;
    for (; j + 4 <= nnodes; j += 4) {
        float v0 = h[(size_t)(node0 + j + 0) * DD + t];
        float v1 = h[(size_t)(node0 + j + 1) * DD + t];
        float v2 = h[(size_t)(node0 + j + 2) * DD + t];
        float v3 = h[(size_t)(node0 + j + 3) * DD + t];
        int g0 = bsh[j + 0], g1 = bsh[j + 1], g2 = bsh[j + 2], g3 = bsh[j + 3];
        #pragma unroll
        for (int u = 0; u < 4; ++u) {
            int g = (u == 0) ? g0 : (u == 1) ? g1 : (u == 2) ? g2 : g3;
            float val = (u == 0) ? v0 : (u == 1) ? v1 : (u == 2) ? v2 : v3;
            if (g != cur) {
                atomicAdd(&gsum[cur * DD + t], acc);
                if (t == 0) atomicAdd(&gcnt[cur], (float)cnt);
                acc = 0.f; cnt = 0; cur = g;
            }
            acc += val; ++cnt;
        }
    }
    for (; j < nnodes; ++j) {
        int g = bsh[j];
        float val = h[(size_t)(node0 + j) * DD + t];
        if (g != cur) {
            atomicAdd(&gsum[cur * DD + t], acc);
            if (t == 0) atomicAdd(&gcnt[cur], (float)cnt);
            acc = 0.f; cnt = 0; cur = g;
        }
        acc += val; ++cnt;
    }
    if (cnt > 0) {
        atomicAdd(&gsum[cur * DD + t], acc);
        if (t == 0) atomicAdd(&gcnt[cur], (float)cnt);
    }
}

// ---------------- FC + log_softmax ----------------

__global__ __launch_bounds__(64) void head_kernel(
    const float* __restrict__ gsum, const float* __restrict__ gcnt,
    const float* __restrict__ wfc, const float* __restrict__ bfc,
    float* __restrict__ out) {
    int g = blockIdx.x;
    int lane = threadIdx.x;
    float cnt = fmaxf(gcnt[g], 1.0f);
    float inv = 1.0f / cnt;
    float p0 = gsum[g * DD + lane] * inv;
    float p1 = gsum[g * DD + lane + 64] * inv;
    __shared__ float logits[NCLS];
    for (int c = 0; c < NCLS; ++c) {
        float partial = p0 * wfc[lane * NCLS + c] + p1 * wfc[(lane + 64) * NCLS + c];
        partial += __shfl_xor(partial, 32);
        partial += __shfl_xor(partial, 16);
        partial += __shfl_xor(partial, 8);
        partial += __shfl_xor(partial, 4);
        partial += __shfl_xor(partial, 2);
        partial += __shfl_xor(partial, 1);
        if (lane == 0) logits[c] = partial + bfc[c];
    }
    __syncthreads();
    if (lane == 0) {
        float mx = logits[0];
        for (int c = 1; c < NCLS; ++c) mx = fmaxf(mx, logits[c]);
        float sum = 0.f;
        for (int c = 0; c < NCLS; ++c) sum += expf(logits[c] - mx);
        float lse = mx + logf(sum);
        for (int c = 0; c < NCLS; ++c) out[g * NCLS + c] = logits[c] - lse;
    }
}

// ---------------- launch ----------------

extern "C" void kernel_launch(void* const* d_in, const int* in_sizes, int n_in,
                              void* d_out, int out_size, void* d_ws, size_t ws_size,
                              hipStream_t stream) {
    const float* x     = (const float*)d_in[0];
    const int*   ei    = (const int*)d_in[1];
    const int*   batch = (const int*)d_in[2];
    const float* Wq = (const float*)d_in[3];
    const float* bq = (const float*)d_in[4];
    const float* Wk = (const float*)d_in[5];
    const float* bk = (const float*)d_in[6];
    const float* Wv = (const float*)d_in[7];
    const float* bv = (const float*)d_in[8];
    const float* Ws = (const float*)d_in[9];
    const float* bs = (const float*)d_in[10];
    const float* Wfc = (const float*)d_in[11];
    const float* bfc = (const float*)d_in[12];
    float* out = (float*)d_out;

    const size_t ND = (size_t)NN * DD;
    float* hbuf = (float*)d_ws;
    float* qb = hbuf + ND;
    float* kb = qb + ND;
    float* vb = kb + ND;
    float* sb = vb + ND;
    int* cnt    = (int*)(sb + ND);
    int* indptr = cnt + NN;
    int* cursor = indptr + NN + 1;
    int* esrc   = cursor + NN;
    float* gsum = (float*)(esrc + EE);
    float* gcnt = gsum + GG * DD;
    unsigned short* wt = (unsigned short*)(gcnt + GG);   // [2][4][128][128] bf16

    const int* src = ei;
    const int* dst = ei + EE;

    hipMemsetAsync(cnt, 0, NN * sizeof(int), stream);
    hipMemsetAsync(gsum, 0, (GG * DD + GG) * sizeof(float), stream);

    hist_kernel<<<(EE + 255) / 256, 256, 0, stream>>>(dst, cnt, EE);
    scan_kernel<<<1, 1024, 0, stream>>>(cnt, indptr, cursor, NN, EE);
    fill_kernel<<<(EE + 255) / 256, 256, 0, stream>>>(src, dst, cursor, esrc, EE);
    wt_kernel<<<512, 256, 0, stream>>>(Wq, Wk, Wv, Ws, wt);

    for (int l = 0; l < 2; ++l) {
        const float* hin = (l == 0) ? x : hbuf;
        size_t bo = (size_t)l * DD;
        gemm_mfma<<<dim3((NN + 127) / 128, 4), 256, 0, stream>>>(
            hin, wt + (size_t)l * 4 * 16384,
            bq + bo, bk + bo, bv + bo, bs + bo,
            qb, kb, vb, sb);
        attn_kernel<<<(NN + 3) / 4, 256, 0, stream>>>(
            qb, kb, vb, sb, indptr, esrc, hbuf, NN);
    }

    pool_kernel<<<(NN + PCHUNK - 1) / PCHUNK, 128, 0, stream>>>(hbuf, batch, gsum, gcnt, NN);
    head_kernel<<<GG, 64, 0, stream>>>(gsum, gcnt, Wfc, bfc, out);
}

// Round 4
// 515.599 us; speedup vs baseline: 2.0003x; 1.0520x over previous
//
#include <hip/hip_runtime.h>
#include <math.h>

#define NN 50000
#define EE 600000
#define DD 128
#define GG 64
#define NCLS 10
#define PCHUNK 128

typedef __attribute__((ext_vector_type(8))) __bf16 bf16x8;
typedef __attribute__((ext_vector_type(8))) unsigned short u16x8;
typedef __attribute__((ext_vector_type(4))) float f32x4;

__device__ __forceinline__ unsigned short f2bf(float f) {
    unsigned int u = __float_as_uint(f);
    u += 0x7fff + ((u >> 16) & 1);     // round-to-nearest-even
    return (unsigned short)(u >> 16);
}

// ---------------- CSR build ----------------

__global__ void hist_kernel(const int* __restrict__ dst, int* __restrict__ cnt, int e) {
    int i = blockIdx.x * blockDim.x + threadIdx.x;
    if (i < e) atomicAdd(&cnt[dst[i]], 1);
}

__global__ __launch_bounds__(1024) void scan_kernel(const int* __restrict__ cnt,
                                                    int* __restrict__ indptr,
                                                    int* __restrict__ cursor,
                                                    int n, int total) {
    __shared__ int wsum[16];
    __shared__ int carry_s;
    int tid = threadIdx.x;
    int lane = tid & 63, wid = tid >> 6;
    if (tid == 0) carry_s = 0;
    __syncthreads();
    for (int base = 0; base < n; base += 1024) {
        int i = base + tid;
        int v = (i < n) ? cnt[i] : 0;
        int x = v;
        #pragma unroll
        for (int off = 1; off < 64; off <<= 1) {
            int y = __shfl_up(x, off);
            if (lane >= off) x += y;
        }
        if (lane == 63) wsum[wid] = x;
        __syncthreads();
        if (wid == 0) {
            int ws = (lane < 16) ? wsum[lane] : 0;
            int xs = ws;
            #pragma unroll
            for (int off = 1; off < 16; off <<= 1) {
                int y = __shfl_up(xs, off);
                if (lane >= off) xs += y;
            }
            if (lane < 16) wsum[lane] = xs - ws;
        }
        __syncthreads();
        int excl = carry_s + wsum[wid] + x - v;
        if (i < n) { indptr[i] = excl; cursor[i] = excl; }
        __syncthreads();
        if (tid == 1023) carry_s += wsum[15] + x;
        __syncthreads();
    }
    if (tid == 0) indptr[n] = total;
}

__global__ void fill_kernel(const int* __restrict__ src, const int* __restrict__ dst,
                            int* __restrict__ cursor, int* __restrict__ esrc, int e) {
    int i = blockIdx.x * blockDim.x + threadIdx.x;
    if (i < e) {
        int pos = atomicAdd(&cursor[dst[i]], 1);
        esrc[pos] = src[i];
    }
}

// ---------------- weight pre-transpose + bf16 convert ----------------

__global__ void wt_kernel(const float* __restrict__ wq, const float* __restrict__ wk,
                          const float* __restrict__ wv, const float* __restrict__ ws,
                          unsigned short* __restrict__ wt) {
    int idx = blockIdx.x * 256 + threadIdx.x;
    int k = idx & 127;
    int n = (idx >> 7) & 127;
    int lm = idx >> 14;
    int l = lm >> 2, m = lm & 3;
    const float* w = (m == 0) ? wq : (m == 1) ? wk : (m == 2) ? wv : ws;
    wt[idx] = f2bf(w[l * 16384 + k * 128 + n]);
}

// ---------------- bf16 MFMA QKVS GEMM ----------------
// q,s written fp32; k,v written bf16 (halves attention gather bytes).

__global__ __launch_bounds__(256) void gemm_mfma(
    const float* __restrict__ x,
    const unsigned short* __restrict__ wt,
    const float* __restrict__ bq, const float* __restrict__ bk,
    const float* __restrict__ bv, const float* __restrict__ bs,
    float* __restrict__ q, unsigned short* __restrict__ kb16,
    unsigned short* __restrict__ vb16, float* __restrict__ s) {
    __shared__ __align__(16) unsigned short As[128 * 136];
    __shared__ __align__(16) unsigned short Bs[128 * 136];

    int t = threadIdx.x;
    int mat = blockIdx.y;
    int row0 = blockIdx.x * 128;

    const unsigned short* wm_ = wt + mat * 16384;
    const float* bias = (mat == 0) ? bq : (mat == 1) ? bk : (mat == 2) ? bv : bs;

    int kg = t & 15, rb = t >> 4;
    #pragma unroll
    for (int i = 0; i < 8; ++i) {
        int row = rb + i * 16;
        int grow = row0 + row;
        float4 f0 = {0.f, 0.f, 0.f, 0.f}, f1 = {0.f, 0.f, 0.f, 0.f};
        if (grow < NN) {
            const float* p = x + (size_t)grow * DD + kg * 8;
            f0 = *(const float4*)p;
            f1 = *(const float4*)(p + 4);
        }
        u16x8 a8;
        a8[0] = f2bf(f0.x); a8[1] = f2bf(f0.y); a8[2] = f2bf(f0.z); a8[3] = f2bf(f0.w);
        a8[4] = f2bf(f1.x); a8[5] = f2bf(f1.y); a8[6] = f2bf(f1.z); a8[7] = f2bf(f1.w);
        *(u16x8*)&As[row * 136 + kg * 8] = a8;
        *(u16x8*)&Bs[row * 136 + kg * 8] = *(const u16x8*)(wm_ + row * 128 + kg * 8);
    }
    __syncthreads();

    int lane = t & 63;
    int wave = t >> 6;
    int wm2 = wave >> 1, wn2 = wave & 1;
    int lr = lane & 15, quad = lane >> 4;

    f32x4 acc[4][4];
    #pragma unroll
    for (int a = 0; a < 4; ++a)
        #pragma unroll
        for (int b = 0; b < 4; ++b)
            acc[a][b] = (f32x4){0.f, 0.f, 0.f, 0.f};

    #pragma unroll
    for (int ks = 0; ks < 4; ++ks) {
        bf16x8 af[4], bfr[4];
        #pragma unroll
        for (int tm = 0; tm < 4; ++tm)
            af[tm] = *(const bf16x8*)&As[(wm2 * 64 + tm * 16 + lr) * 136 + ks * 32 + quad * 8];
        #pragma unroll
        for (int tn = 0; tn < 4; ++tn)
            bfr[tn] = *(const bf16x8*)&Bs[(wn2 * 64 + tn * 16 + lr) * 136 + ks * 32 + quad * 8];
        #pragma unroll
        for (int tm = 0; tm < 4; ++tm)
            #pragma unroll
            for (int tn = 0; tn < 4; ++tn)
                acc[tm][tn] = __builtin_amdgcn_mfma_f32_16x16x32_bf16(
                    af[tm], bfr[tn], acc[tm][tn], 0, 0, 0);
    }

    // C/D layout: col = lane&15, row = quad*4 + reg
    if (mat == 0 || mat == 3) {
        float* out = (mat == 0) ? q : s;
        #pragma unroll
        for (int tn = 0; tn < 4; ++tn) {
            int col = wn2 * 64 + tn * 16 + lr;
            float bv_ = bias[col];
            #pragma unroll
            for (int tm = 0; tm < 4; ++tm) {
                int nb = row0 + wm2 * 64 + tm * 16 + quad * 4;
                #pragma unroll
                for (int r = 0; r < 4; ++r) {
                    int node = nb + r;
                    if (node < NN)
                        out[(size_t)node * DD + col] = acc[tm][tn][r] + bv_;
                }
            }
        }
    } else {
        unsigned short* out = (mat == 1) ? kb16 : vb16;
        #pragma unroll
        for (int tn = 0; tn < 4; ++tn) {
            int col = wn2 * 64 + tn * 16 + lr;
            float bv_ = bias[col];
            #pragma unroll
            for (int tm = 0; tm < 4; ++tm) {
                int nb = row0 + wm2 * 64 + tm * 16 + quad * 4;
                #pragma unroll
                for (int r = 0; r < 4; ++r) {
                    int node = nb + r;
                    if (node < NN)
                        out[(size_t)node * DD + col] = f2bf(acc[tm][tn][r] + bv_);
                }
            }
        }
    }
}

// ---------------- per-node online-softmax attention ----------------
// lane owns paired channels {2*lane, 2*lane+1}: one dword gather per row.

__global__ __launch_bounds__(256) void attn_kernel(
    const float* __restrict__ q, const unsigned short* __restrict__ kb16,
    const unsigned short* __restrict__ vb16, const float* __restrict__ s,
    const int* __restrict__ indptr, const int* __restrict__ esrc,
    float* __restrict__ hout, int n) {
    int node = (int)((blockIdx.x * blockDim.x + threadIdx.x) >> 6);
    int lane = threadIdx.x & 63;
    if (node >= n) return;

    float2 qv = *(const float2*)(q + (size_t)node * DD + 2 * lane);
    int beg = indptr[node], end = indptr[node + 1];

    float m = -INFINITY, den = 0.f, a0 = 0.f, a1 = 0.f;
    for (int e = beg; e < end; ++e) {
        int sidx = esrc[e];
        unsigned int ku = *(const unsigned int*)(kb16 + (size_t)sidx * DD + 2 * lane);
        unsigned int vu = *(const unsigned int*)(vb16 + (size_t)sidx * DD + 2 * lane);
        float k0 = __uint_as_float(ku << 16);
        float k1 = __uint_as_float(ku & 0xffff0000u);
        float p = qv.x * k0 + qv.y * k1;
        p += __shfl_xor(p, 32);
        p += __shfl_xor(p, 16);
        p += __shfl_xor(p, 8);
        p += __shfl_xor(p, 4);
        p += __shfl_xor(p, 2);
        p += __shfl_xor(p, 1);
        float score = p * 0.088388347648318447f;   // 1/sqrt(128)
        float mn = fmaxf(m, score);
        float scale = __expf(m - mn);
        float pe = __expf(score - mn);
        float v0 = __uint_as_float(vu << 16);
        float v1 = __uint_as_float(vu & 0xffff0000u);
        den = den * scale + pe;
        a0 = a0 * scale + pe * v0;
        a1 = a1 * scale + pe * v1;
        m = mn;
    }
    float inv = den > 0.f ? 1.0f / den : 0.f;
    float2 sv = *(const float2*)(s + (size_t)node * DD + 2 * lane);
    float2 o;
    o.x = fmaxf(fmaf(a0, inv, sv.x), 0.f);
    o.y = fmaxf(fmaf(a1, inv, sv.y), 0.f);
    *(float2*)(hout + (size_t)node * DD + 2 * lane) = o;
}

// ---------------- global mean pool: segmented running sum ----------------

__global__ __launch_bounds__(128) void pool_kernel(const float* __restrict__ h,
                                                   const int* __restrict__ batch,
                                                   float* __restrict__ gsum,
                                                   float* __restrict__ gcnt, int n) {
    __shared__ int bsh[PCHUNK];
    int t = threadIdx.x;
    int node0 = blockIdx.x * PCHUNK;
    int nnodes = min(PCHUNK, n - node0);
    if (t < nnodes) bsh[t] = batch[node0 + t];
    __syncthreads();

    int cur = bsh[0];
    float acc = 0.f;
    int cnt = 0;
    int j = 0;
    for (; j + 4 <= nnodes; j += 4) {
        float v0 = h[(size_t)(node0 + j + 0) * DD + t];
        float v1 = h[(size_t)(node0 + j + 1) * DD + t];
        float v2 = h[(size_t)(node0 + j + 2) * DD + t];
        float v3 = h[(size_t)(node0 + j + 3) * DD + t];
        int g0 = bsh[j + 0], g1 = bsh[j + 1], g2 = bsh[j + 2], g3 = bsh[j + 3];
        #pragma unroll
        for (int u = 0; u < 4; ++u) {
            int g = (u == 0) ? g0 : (u == 1) ? g1 : (u == 2) ? g2 : g3;
            float val = (u == 0) ? v0 : (u == 1) ? v1 : (u == 2) ? v2 : v3;
            if (g != cur) {
                atomicAdd(&gsum[cur * DD + t], acc);
                if (t == 0) atomicAdd(&gcnt[cur], (float)cnt);
                acc = 0.f; cnt = 0; cur = g;
            }
            acc += val; ++cnt;
        }
    }
    for (; j < nnodes; ++j) {
        int g = bsh[j];
        float val = h[(size_t)(node0 + j) * DD + t];
        if (g != cur) {
            atomicAdd(&gsum[cur * DD + t], acc);
            if (t == 0) atomicAdd(&gcnt[cur], (float)cnt);
            acc = 0.f; cnt = 0; cur = g;
        }
        acc += val; ++cnt;
    }
    if (cnt > 0) {
        atomicAdd(&gsum[cur * DD + t], acc);
        if (t == 0) atomicAdd(&gcnt[cur], (float)cnt);
    }
}

// ---------------- FC + log_softmax ----------------

__global__ __launch_bounds__(64) void head_kernel(
    const float* __restrict__ gsum, const float* __restrict__ gcnt,
    const float* __restrict__ wfc, const float* __restrict__ bfc,
    float* __restrict__ out) {
    int g = blockIdx.x;
    int lane = threadIdx.x;
    float cnt = fmaxf(gcnt[g], 1.0f);
    float inv = 1.0f / cnt;
    float p0 = gsum[g * DD + lane] * inv;
    float p1 = gsum[g * DD + lane + 64] * inv;
    __shared__ float logits[NCLS];
    for (int c = 0; c < NCLS; ++c) {
        float partial = p0 * wfc[lane * NCLS + c] + p1 * wfc[(lane + 64) * NCLS + c];
        partial += __shfl_xor(partial, 32);
        partial += __shfl_xor(partial, 16);
        partial += __shfl_xor(partial, 8);
        partial += __shfl_xor(partial, 4);
        partial += __shfl_xor(partial, 2);
        partial += __shfl_xor(partial, 1);
        if (lane == 0) logits[c] = partial + bfc[c];
    }
    __syncthreads();
    if (lane == 0) {
        float mx = logits[0];
        for (int c = 1; c < NCLS; ++c) mx = fmaxf(mx, logits[c]);
        float sum = 0.f;
        for (int c = 0; c < NCLS; ++c) sum += expf(logits[c] - mx);
        float lse = mx + logf(sum);
        for (int c = 0; c < NCLS; ++c) out[g * NCLS + c] = logits[c] - lse;
    }
}

// ---------------- launch ----------------

extern "C" void kernel_launch(void* const* d_in, const int* in_sizes, int n_in,
                              void* d_out, int out_size, void* d_ws, size_t ws_size,
                              hipStream_t stream) {
    const float* x     = (const float*)d_in[0];
    const int*   ei    = (const int*)d_in[1];
    const int*   batch = (const int*)d_in[2];
    const float* Wq = (const float*)d_in[3];
    const float* bq = (const float*)d_in[4];
    const float* Wk = (const float*)d_in[5];
    const float* bk = (const float*)d_in[6];
    const float* Wv = (const float*)d_in[7];
    const float* bv = (const float*)d_in[8];
    const float* Ws = (const float*)d_in[9];
    const float* bs = (const float*)d_in[10];
    const float* Wfc = (const float*)d_in[11];
    const float* bfc = (const float*)d_in[12];
    float* out = (float*)d_out;

    const size_t ND = (size_t)NN * DD;
    float* hbuf = (float*)d_ws;
    float* qb = hbuf + ND;
    float* sb = qb + ND;
    unsigned short* kb16 = (unsigned short*)(sb + ND);   // ND ushorts
    unsigned short* vb16 = kb16 + ND;
    int* cnt    = (int*)(vb16 + ND);
    int* indptr = cnt + NN;
    int* cursor = indptr + NN + 1;
    int* esrc   = cursor + NN;
    float* gsum = (float*)(esrc + EE);
    float* gcnt = gsum + GG * DD;
    unsigned short* wt = (unsigned short*)(gcnt + GG);   // [2][4][128][128] bf16

    const int* src = ei;
    const int* dst = ei + EE;

    hipMemsetAsync(cnt, 0, NN * sizeof(int), stream);
    hipMemsetAsync(gsum, 0, (GG * DD + GG) * sizeof(float), stream);

    hist_kernel<<<(EE + 255) / 256, 256, 0, stream>>>(dst, cnt, EE);
    scan_kernel<<<1, 1024, 0, stream>>>(cnt, indptr, cursor, NN, EE);
    fill_kernel<<<(EE + 255) / 256, 256, 0, stream>>>(src, dst, cursor, esrc, EE);
    wt_kernel<<<512, 256, 0, stream>>>(Wq, Wk, Wv, Ws, wt);

    for (int l = 0; l < 2; ++l) {
        const float* hin = (l == 0) ? x : hbuf;
        size_t bo = (size_t)l * DD;
        gemm_mfma<<<dim3((NN + 127) / 128, 4), 256, 0, stream>>>(
            hin, wt + (size_t)l * 4 * 16384,
            bq + bo, bk + bo, bv + bo, bs + bo,
            qb, kb16, vb16, sb);
        attn_kernel<<<(NN + 3) / 4, 256, 0, stream>>>(
            qb, kb16, vb16, sb, indptr, esrc, hbuf, NN);
    }

    pool_kernel<<<(NN + PCHUNK - 1) / PCHUNK, 128, 0, stream>>>(hbuf, batch, gsum, gcnt, NN);
    head_kernel<<<GG, 64, 0, stream>>>(gsum, gcnt, Wfc, bfc, out);
}

// Round 5
// 397.729 us; speedup vs baseline: 2.5930x; 1.2964x over previous
//
#include <hip/hip_runtime.h>
#include <math.h>

#define NN 50000
#define EE 600000
#define DD 128
#define GG 64
#define NCLS 10
#define PCHUNK 128
#define SCHUNK 1024
#define NCHUNK ((NN + SCHUNK - 1) / SCHUNK)

typedef __attribute__((ext_vector_type(8))) __bf16 bf16x8;
typedef __attribute__((ext_vector_type(8))) unsigned short u16x8;
typedef __attribute__((ext_vector_type(4))) float f32x4;

__device__ __forceinline__ unsigned short f2bf(float f) {
    unsigned int u = __float_as_uint(f);
    u += 0x7fff + ((u >> 16) & 1);     // round-to-nearest-even
    return (unsigned short)(u >> 16);
}

__device__ __forceinline__ float bf2f(unsigned short h) {
    return __uint_as_float(((unsigned int)h) << 16);
}

// ---------------- CSR build ----------------

__global__ void hist_kernel(const int* __restrict__ dst, int* __restrict__ cnt, int e) {
    int i = blockIdx.x * blockDim.x + threadIdx.x;
    if (i < e) atomicAdd(&cnt[dst[i]], 1);
}

// phase 1: per-chunk local exclusive scan + chunk totals
__global__ __launch_bounds__(1024) void scan1_kernel(const int* __restrict__ cnt,
                                                     int* __restrict__ lexcl,
                                                     int* __restrict__ csum, int n) {
    __shared__ int wsum[16];
    int tid = threadIdx.x;
    int lane = tid & 63, wid = tid >> 6;
    int i = blockIdx.x * SCHUNK + tid;
    int v = (i < n) ? cnt[i] : 0;
    int x = v;
    #pragma unroll
    for (int off = 1; off < 64; off <<= 1) {
        int y = __shfl_up(x, off);
        if (lane >= off) x += y;
    }
    if (lane == 63) wsum[wid] = x;
    __syncthreads();
    if (wid == 0) {
        int ws = (lane < 16) ? wsum[lane] : 0;
        int xs = ws;
        #pragma unroll
        for (int off = 1; off < 16; off <<= 1) {
            int y = __shfl_up(xs, off);
            if (lane >= off) xs += y;
        }
        if (lane < 16) wsum[lane] = xs - ws;
    }
    __syncthreads();
    if (i < n) lexcl[i] = wsum[wid] + x - v;
    if (tid == 1023) csum[blockIdx.x] = wsum[15] + x;
}

// phase 2: exclusive scan of chunk totals (one wave)
__global__ __launch_bounds__(64) void scan2_kernel(int* __restrict__ csum, int nchunk) {
    int lane = threadIdx.x;
    int v = (lane < nchunk) ? csum[lane] : 0;
    int x = v;
    #pragma unroll
    for (int off = 1; off < 64; off <<= 1) {
        int y = __shfl_up(x, off);
        if (lane >= off) x += y;
    }
    if (lane < nchunk) csum[lane] = x - v;
}

// phase 3: add chunk base, write indptr + cursor
__global__ __launch_bounds__(1024) void scan3_kernel(const int* __restrict__ lexcl,
                                                     const int* __restrict__ csum,
                                                     int* __restrict__ indptr,
                                                     int* __restrict__ cursor,
                                                     int n, int total) {
    int i = blockIdx.x * SCHUNK + threadIdx.x;
    if (i < n) {
        int val = lexcl[i] + csum[blockIdx.x];
        indptr[i] = val;
        cursor[i] = val;
    }
    if (i == 0) indptr[n] = total;
}

__global__ void fill_kernel(const int* __restrict__ src, const int* __restrict__ dst,
                            int* __restrict__ cursor, int* __restrict__ esrc, int e) {
    int i = blockIdx.x * blockDim.x + threadIdx.x;
    if (i < e) {
        int pos = atomicAdd(&cursor[dst[i]], 1);
        esrc[pos] = src[i];
    }
}

// ---------------- weight pre-transpose + bf16 convert ----------------

__global__ void wt_kernel(const float* __restrict__ wq, const float* __restrict__ wk,
                          const float* __restrict__ wv, const float* __restrict__ ws,
                          unsigned short* __restrict__ wt) {
    int idx = blockIdx.x * 256 + threadIdx.x;
    int k = idx & 127;
    int n = (idx >> 7) & 127;
    int lm = idx >> 14;
    int l = lm >> 2, m = lm & 3;
    const float* w = (m == 0) ? wq : (m == 1) ? wk : (m == 2) ? wv : ws;
    wt[idx] = f2bf(w[l * 16384 + k * 128 + n]);
}

// ---------------- bf16 MFMA QKVS GEMM ----------------

__global__ __launch_bounds__(256) void gemm_mfma(
    const float* __restrict__ x,
    const unsigned short* __restrict__ wt,
    const float* __restrict__ bq, const float* __restrict__ bk,
    const float* __restrict__ bv, const float* __restrict__ bs,
    float* __restrict__ q, unsigned short* __restrict__ kb16,
    unsigned short* __restrict__ vb16, float* __restrict__ s) {
    __shared__ __align__(16) unsigned short As[128 * 136];
    __shared__ __align__(16) unsigned short Bs[128 * 136];

    int t = threadIdx.x;
    int mat = blockIdx.y;
    int row0 = blockIdx.x * 128;

    const unsigned short* wm_ = wt + mat * 16384;
    const float* bias = (mat == 0) ? bq : (mat == 1) ? bk : (mat == 2) ? bv : bs;

    int kg = t & 15, rb = t >> 4;
    #pragma unroll
    for (int i = 0; i < 8; ++i) {
        int row = rb + i * 16;
        int grow = row0 + row;
        float4 f0 = {0.f, 0.f, 0.f, 0.f}, f1 = {0.f, 0.f, 0.f, 0.f};
        if (grow < NN) {
            const float* p = x + (size_t)grow * DD + kg * 8;
            f0 = *(const float4*)p;
            f1 = *(const float4*)(p + 4);
        }
        u16x8 a8;
        a8[0] = f2bf(f0.x); a8[1] = f2bf(f0.y); a8[2] = f2bf(f0.z); a8[3] = f2bf(f0.w);
        a8[4] = f2bf(f1.x); a8[5] = f2bf(f1.y); a8[6] = f2bf(f1.z); a8[7] = f2bf(f1.w);
        *(u16x8*)&As[row * 136 + kg * 8] = a8;
        *(u16x8*)&Bs[row * 136 + kg * 8] = *(const u16x8*)(wm_ + row * 128 + kg * 8);
    }
    __syncthreads();

    int lane = t & 63;
    int wave = t >> 6;
    int wm2 = wave >> 1, wn2 = wave & 1;
    int lr = lane & 15, quad = lane >> 4;

    f32x4 acc[4][4];
    #pragma unroll
    for (int a = 0; a < 4; ++a)
        #pragma unroll
        for (int b = 0; b < 4; ++b)
            acc[a][b] = (f32x4){0.f, 0.f, 0.f, 0.f};

    #pragma unroll
    for (int ks = 0; ks < 4; ++ks) {
        bf16x8 af[4], bfr[4];
        #pragma unroll
        for (int tm = 0; tm < 4; ++tm)
            af[tm] = *(const bf16x8*)&As[(wm2 * 64 + tm * 16 + lr) * 136 + ks * 32 + quad * 8];
        #pragma unroll
        for (int tn = 0; tn < 4; ++tn)
            bfr[tn] = *(const bf16x8*)&Bs[(wn2 * 64 + tn * 16 + lr) * 136 + ks * 32 + quad * 8];
        #pragma unroll
        for (int tm = 0; tm < 4; ++tm)
            #pragma unroll
            for (int tn = 0; tn < 4; ++tn)
                acc[tm][tn] = __builtin_amdgcn_mfma_f32_16x16x32_bf16(
                    af[tm], bfr[tn], acc[tm][tn], 0, 0, 0);
    }

    // C/D layout: col = lane&15, row = quad*4 + reg
    if (mat == 0 || mat == 3) {
        float* out = (mat == 0) ? q : s;
        #pragma unroll
        for (int tn = 0; tn < 4; ++tn) {
            int col = wn2 * 64 + tn * 16 + lr;
            float bv_ = bias[col];
            #pragma unroll
            for (int tm = 0; tm < 4; ++tm) {
                int nb = row0 + wm2 * 64 + tm * 16 + quad * 4;
                #pragma unroll
                for (int r = 0; r < 4; ++r) {
                    int node = nb + r;
                    if (node < NN)
                        out[(size_t)node * DD + col] = acc[tm][tn][r] + bv_;
                }
            }
        }
    } else {
        unsigned short* out = (mat == 1) ? kb16 : vb16;
        #pragma unroll
        for (int tn = 0; tn < 4; ++tn) {
            int col = wn2 * 64 + tn * 16 + lr;
            float bv_ = bias[col];
            #pragma unroll
            for (int tm = 0; tm < 4; ++tm) {
                int nb = row0 + wm2 * 64 + tm * 16 + quad * 4;
                #pragma unroll
                for (int r = 0; r < 4; ++r) {
                    int node = nb + r;
                    if (node < NN)
                        out[(size_t)node * DD + col] = f2bf(acc[tm][tn][r] + bv_);
                }
            }
        }
    }
}

// ---------------- attention: 4 edges/wave via 16-lane subgroups ----------------
// subgroup g = lane>>4 processes edges beg+g, beg+g+4, ...; lane j=lane&15 owns
// channels 8j..8j+7. Online-softmax state per subgroup, merged once at the end.

__global__ __launch_bounds__(256) void attn_kernel(
    const float* __restrict__ q, const unsigned short* __restrict__ kb16,
    const unsigned short* __restrict__ vb16, const float* __restrict__ s,
    const int* __restrict__ indptr, const int* __restrict__ esrc,
    float* __restrict__ hout, int n) {
    int node = (int)((blockIdx.x * blockDim.x + threadIdx.x) >> 6);
    int lane = threadIdx.x & 63;
    if (node >= n) return;
    int g = lane >> 4, j = lane & 15;

    const float* qp = q + (size_t)node * DD + j * 8;
    float4 q0 = *(const float4*)qp;
    float4 q1 = *(const float4*)(qp + 4);

    int beg = indptr[node], end = indptr[node + 1];

    float m = -3.0e38f, den = 0.f;
    float acc[8];
    #pragma unroll
    for (int c = 0; c < 8; ++c) acc[c] = 0.f;

    for (int e = beg + g; e < end; e += 4) {
        int sidx = esrc[e];
        u16x8 k8 = *(const u16x8*)(kb16 + (size_t)sidx * DD + j * 8);
        u16x8 v8 = *(const u16x8*)(vb16 + (size_t)sidx * DD + j * 8);
        float p;
        p  = q0.x * bf2f(k8[0]);
        p  = fmaf(q0.y, bf2f(k8[1]), p);
        p  = fmaf(q0.z, bf2f(k8[2]), p);
        p  = fmaf(q0.w, bf2f(k8[3]), p);
        p  = fmaf(q1.x, bf2f(k8[4]), p);
        p  = fmaf(q1.y, bf2f(k8[5]), p);
        p  = fmaf(q1.z, bf2f(k8[6]), p);
        p  = fmaf(q1.w, bf2f(k8[7]), p);
        // reduce across the 16-lane subgroup
        p += __shfl_xor(p, 8);
        p += __shfl_xor(p, 4);
        p += __shfl_xor(p, 2);
        p += __shfl_xor(p, 1);
        float score = p * 0.088388347648318447f;   // 1/sqrt(128)
        float mn = fmaxf(m, score);
        float scale = __expf(m - mn);
        float pe = __expf(score - mn);
        den = den * scale + pe;
        #pragma unroll
        for (int c = 0; c < 8; ++c)
            acc[c] = fmaf(acc[c], scale, pe * bf2f(v8[c]));
        m = mn;
    }

    // merge the 4 subgroup states (finite m0 => no inf-inf NaN)
    float mo = __shfl_xor(m, 16);
    float m2 = fmaxf(m, mo);
    mo = __shfl_xor(m2, 32);
    float mf = fmaxf(m2, mo);
    float sc = __expf(m - mf);
    den *= sc;
    den += __shfl_xor(den, 16);
    den += __shfl_xor(den, 32);
    #pragma unroll
    for (int c = 0; c < 8; ++c) {
        float a = acc[c] * sc;
        a += __shfl_xor(a, 16);
        a += __shfl_xor(a, 32);
        acc[c] = a;
    }
    float inv = den > 0.f ? 1.0f / den : 0.f;
    if (g == 0) {
        const float* sp = s + (size_t)node * DD + j * 8;
        float4 s0 = *(const float4*)sp;
        float4 s1 = *(const float4*)(sp + 4);
        float4 o0, o1;
        o0.x = fmaxf(fmaf(acc[0], inv, s0.x), 0.f);
        o0.y = fmaxf(fmaf(acc[1], inv, s0.y), 0.f);
        o0.z = fmaxf(fmaf(acc[2], inv, s0.z), 0.f);
        o0.w = fmaxf(fmaf(acc[3], inv, s0.w), 0.f);
        o1.x = fmaxf(fmaf(acc[4], inv, s1.x), 0.f);
        o1.y = fmaxf(fmaf(acc[5], inv, s1.y), 0.f);
        o1.z = fmaxf(fmaf(acc[6], inv, s1.z), 0.f);
        o1.w = fmaxf(fmaf(acc[7], inv, s1.w), 0.f);
        float* op = hout + (size_t)node * DD + j * 8;
        *(float4*)op = o0;
        *(float4*)(op + 4) = o1;
    }
}

// ---------------- global mean pool: segmented running sum ----------------

__global__ __launch_bounds__(128) void pool_kernel(const float* __restrict__ h,
                                                   const int* __restrict__ batch,
                                                   float* __restrict__ gsum,
                                                   float* __restrict__ gcnt, int n) {
    __shared__ int bsh[PCHUNK];
    int t = threadIdx.x;
    int node0 = blockIdx.x * PCHUNK;
    int nnodes = min(PCHUNK, n - node0);
    if (t < nnodes) bsh[t] = batch[node0 + t];
    __syncthreads();

    int cur = bsh[0];
    float acc = 0.f;
    int cnt = 0;
    int j = 0;
    for (; j + 4 <= nnodes; j += 4) {
        float v0 = h[(size_t)(node0 + j + 0) * DD + t];
        float v1 = h[(size_t)(node0 + j + 1) * DD + t];
        float v2 = h[(size_t)(node0 + j + 2) * DD + t];
        float v3 = h[(size_t)(node0 + j + 3) * DD + t];
        int g0 = bsh[j + 0], g1 = bsh[j + 1], g2 = bsh[j + 2], g3 = bsh[j + 3];
        #pragma unroll
        for (int u = 0; u < 4; ++u) {
            int g = (u == 0) ? g0 : (u == 1) ? g1 : (u == 2) ? g2 : g3;
            float val = (u == 0) ? v0 : (u == 1) ? v1 : (u == 2) ? v2 : v3;
            if (g != cur) {
                atomicAdd(&gsum[cur * DD + t], acc);
                if (t == 0) atomicAdd(&gcnt[cur], (float)cnt);
                acc = 0.f; cnt = 0; cur = g;
            }
            acc += val; ++cnt;
        }
    }
    for (; j < nnodes; ++j) {
        int g = bsh[j];
        float val = h[(size_t)(node0 + j) * DD + t];
        if (g != cur) {
            atomicAdd(&gsum[cur * DD + t], acc);
            if (t == 0) atomicAdd(&gcnt[cur], (float)cnt);
            acc = 0.f; cnt = 0; cur = g;
        }
        acc += val; ++cnt;
    }
    if (cnt > 0) {
        atomicAdd(&gsum[cur * DD + t], acc);
        if (t == 0) atomicAdd(&gcnt[cur], (float)cnt);
    }
}

// ---------------- FC + log_softmax ----------------

__global__ __launch_bounds__(64) void head_kernel(
    const float* __restrict__ gsum, const float* __restrict__ gcnt,
    const float* __restrict__ wfc, const float* __restrict__ bfc,
    float* __restrict__ out) {
    int g = blockIdx.x;
    int lane = threadIdx.x;
    float cnt = fmaxf(gcnt[g], 1.0f);
    float inv = 1.0f / cnt;
    float p0 = gsum[g * DD + lane] * inv;
    float p1 = gsum[g * DD + lane + 64] * inv;
    __shared__ float logits[NCLS];
    for (int c = 0; c < NCLS; ++c) {
        float partial = p0 * wfc[lane * NCLS + c] + p1 * wfc[(lane + 64) * NCLS + c];
        partial += __shfl_xor(partial, 32);
        partial += __shfl_xor(partial, 16);
        partial += __shfl_xor(partial, 8);
        partial += __shfl_xor(partial, 4);
        partial += __shfl_xor(partial, 2);
        partial += __shfl_xor(partial, 1);
        if (lane == 0) logits[c] = partial + bfc[c];
    }
    __syncthreads();
    if (lane == 0) {
        float mx = logits[0];
        for (int c = 1; c < NCLS; ++c) mx = fmaxf(mx, logits[c]);
        float sum = 0.f;
        for (int c = 0; c < NCLS; ++c) sum += expf(logits[c] - mx);
        float lse = mx + logf(sum);
        for (int c = 0; c < NCLS; ++c) out[g * NCLS + c] = logits[c] - lse;
    }
}

// ---------------- launch ----------------

extern "C" void kernel_launch(void* const* d_in, const int* in_sizes, int n_in,
                              void* d_out, int out_size, void* d_ws, size_t ws_size,
                              hipStream_t stream) {
    const float* x     = (const float*)d_in[0];
    const int*   ei    = (const int*)d_in[1];
    const int*   batch = (const int*)d_in[2];
    const float* Wq = (const float*)d_in[3];
    const float* bq = (const float*)d_in[4];
    const float* Wk = (const float*)d_in[5];
    const float* bk = (const float*)d_in[6];
    const float* Wv = (const float*)d_in[7];
    const float* bv = (const float*)d_in[8];
    const float* Ws = (const float*)d_in[9];
    const float* bs = (const float*)d_in[10];
    const float* Wfc = (const float*)d_in[11];
    const float* bfc = (const float*)d_in[12];
    float* out = (float*)d_out;

    const size_t ND = (size_t)NN * DD;
    float* hbuf = (float*)d_ws;
    float* qb = hbuf + ND;
    float* sb = qb + ND;
    unsigned short* kb16 = (unsigned short*)(sb + ND);
    unsigned short* vb16 = kb16 + ND;
    int* cnt    = (int*)(vb16 + ND);
    int* indptr = cnt + NN;
    int* cursor = indptr + NN + 1;
    int* esrc   = cursor + NN;
    int* lexcl  = esrc + EE;
    int* csum   = lexcl + NN;
    float* gsum = (float*)(csum + NCHUNK);
    float* gcnt = gsum + GG * DD;
    unsigned short* wt = (unsigned short*)(gcnt + GG);

    const int* src = ei;
    const int* dst = ei + EE;

    hipMemsetAsync(cnt, 0, NN * sizeof(int), stream);
    hipMemsetAsync(gsum, 0, (GG * DD + GG) * sizeof(float), stream);

    hist_kernel<<<(EE + 255) / 256, 256, 0, stream>>>(dst, cnt, EE);
    scan1_kernel<<<NCHUNK, 1024, 0, stream>>>(cnt, lexcl, csum, NN);
    scan2_kernel<<<1, 64, 0, stream>>>(csum, NCHUNK);
    scan3_kernel<<<NCHUNK, 1024, 0, stream>>>(lexcl, csum, indptr, cursor, NN, EE);
    fill_kernel<<<(EE + 255) / 256, 256, 0, stream>>>(src, dst, cursor, esrc, EE);
    wt_kernel<<<512, 256, 0, stream>>>(Wq, Wk, Wv, Ws, wt);

    for (int l = 0; l < 2; ++l) {
        const float* hin = (l == 0) ? x : hbuf;
        size_t bo = (size_t)l * DD;
        gemm_mfma<<<dim3((NN + 127) / 128, 4), 256, 0, stream>>>(
            hin, wt + (size_t)l * 4 * 16384,
            bq + bo, bk + bo, bv + bo, bs + bo,
            qb, kb16, vb16, sb);
        attn_kernel<<<(NN + 3) / 4, 256, 0, stream>>>(
            qb, kb16, vb16, sb, indptr, esrc, hbuf, NN);
    }

    pool_kernel<<<(NN + PCHUNK - 1) / PCHUNK, 128, 0, stream>>>(hbuf, batch, gsum, gcnt, NN);
    head_kernel<<<GG, 64, 0, stream>>>(gsum, gcnt, Wfc, bfc, out);
}

// Round 6
// 376.293 us; speedup vs baseline: 2.7408x; 1.0570x over previous
//
#include <hip/hip_runtime.h>
#include <math.h>

#define NN 50000
#define EE 600000
#define DD 128
#define GG 64
#define NCLS 10
#define PCHUNK 128
#define SCHUNK 1024
#define NCHUNK ((NN + SCHUNK - 1) / SCHUNK)

typedef __attribute__((ext_vector_type(8))) __bf16 bf16x8;
typedef __attribute__((ext_vector_type(8))) unsigned short u16x8;
typedef __attribute__((ext_vector_type(4))) float f32x4;

__device__ __forceinline__ unsigned short f2bf(float f) {
    unsigned int u = __float_as_uint(f);
    u += 0x7fff + ((u >> 16) & 1);     // round-to-nearest-even
    return (unsigned short)(u >> 16);
}

__device__ __forceinline__ float bf2f(unsigned short h) {
    return __uint_as_float(((unsigned int)h) << 16);
}

// ---------------- CSR build ----------------

__global__ void hist_kernel(const int* __restrict__ dst, int* __restrict__ cnt, int e) {
    int i = blockIdx.x * blockDim.x + threadIdx.x;
    if (i < e) atomicAdd(&cnt[dst[i]], 1);
}

__global__ __launch_bounds__(1024) void scan1_kernel(const int* __restrict__ cnt,
                                                     int* __restrict__ lexcl,
                                                     int* __restrict__ csum, int n) {
    __shared__ int wsum[16];
    int tid = threadIdx.x;
    int lane = tid & 63, wid = tid >> 6;
    int i = blockIdx.x * SCHUNK + tid;
    int v = (i < n) ? cnt[i] : 0;
    int x = v;
    #pragma unroll
    for (int off = 1; off < 64; off <<= 1) {
        int y = __shfl_up(x, off);
        if (lane >= off) x += y;
    }
    if (lane == 63) wsum[wid] = x;
    __syncthreads();
    if (wid == 0) {
        int ws = (lane < 16) ? wsum[lane] : 0;
        int xs = ws;
        #pragma unroll
        for (int off = 1; off < 16; off <<= 1) {
            int y = __shfl_up(xs, off);
            if (lane >= off) xs += y;
        }
        if (lane < 16) wsum[lane] = xs - ws;
    }
    __syncthreads();
    if (i < n) lexcl[i] = wsum[wid] + x - v;
    if (tid == 1023) csum[blockIdx.x] = wsum[15] + x;
}

__global__ __launch_bounds__(64) void scan2_kernel(int* __restrict__ csum, int nchunk) {
    int lane = threadIdx.x;
    int v = (lane < nchunk) ? csum[lane] : 0;
    int x = v;
    #pragma unroll
    for (int off = 1; off < 64; off <<= 1) {
        int y = __shfl_up(x, off);
        if (lane >= off) x += y;
    }
    if (lane < nchunk) csum[lane] = x - v;
}

__global__ __launch_bounds__(1024) void scan3_kernel(const int* __restrict__ lexcl,
                                                     const int* __restrict__ csum,
                                                     int* __restrict__ indptr,
                                                     int* __restrict__ cursor,
                                                     int n, int total) {
    int i = blockIdx.x * SCHUNK + threadIdx.x;
    if (i < n) {
        int val = lexcl[i] + csum[blockIdx.x];
        indptr[i] = val;
        cursor[i] = val;
    }
    if (i == 0) indptr[n] = total;
}

__global__ void fill_kernel(const int* __restrict__ src, const int* __restrict__ dst,
                            int* __restrict__ cursor, int* __restrict__ esrc, int e) {
    int i = blockIdx.x * blockDim.x + threadIdx.x;
    if (i < e) {
        int pos = atomicAdd(&cursor[dst[i]], 1);
        esrc[pos] = src[i];
    }
}

// ---------------- weight pre-transpose + bf16 convert ----------------

__global__ void wt_kernel(const float* __restrict__ wq, const float* __restrict__ wk,
                          const float* __restrict__ wv, const float* __restrict__ ws,
                          unsigned short* __restrict__ wt) {
    int idx = blockIdx.x * 256 + threadIdx.x;
    int k = idx & 127;
    int n = (idx >> 7) & 127;
    int lm = idx >> 14;
    int l = lm >> 2, m = lm & 3;
    const float* w = (m == 0) ? wq : (m == 1) ? wk : (m == 2) ? wv : ws;
    wt[idx] = f2bf(w[l * 16384 + k * 128 + n]);
}

// ---------------- bf16 MFMA QKVS GEMM: 64-row strip, all 4 mats per block ----
// A staged once in LDS (17.4 KB); B fragments read straight from global wt
// (n-major layout == B-fragment order; 32 KB/mat, L2-resident).

__global__ __launch_bounds__(256) void gemm_mfma(
    const float* __restrict__ x,
    const unsigned short* __restrict__ wt,      // [4][128][128] bf16, n-major
    const float* __restrict__ bq, const float* __restrict__ bk,
    const float* __restrict__ bv, const float* __restrict__ bs,
    float* __restrict__ q, unsigned short* __restrict__ kb16,
    unsigned short* __restrict__ vb16, float* __restrict__ s) {
    __shared__ __align__(16) unsigned short As[64 * 136];

    int t = threadIdx.x;
    int row0 = blockIdx.x * 64;

    int kg = t & 15, rb = t >> 4;               // rb 0..15
    #pragma unroll
    for (int i = 0; i < 4; ++i) {
        int row = rb + i * 16;                  // 0..63
        int grow = row0 + row;
        float4 f0 = {0.f, 0.f, 0.f, 0.f}, f1 = {0.f, 0.f, 0.f, 0.f};
        if (grow < NN) {
            const float* p = x + (size_t)grow * DD + kg * 8;
            f0 = *(const float4*)p;
            f1 = *(const float4*)(p + 4);
        }
        u16x8 a8;
        a8[0] = f2bf(f0.x); a8[1] = f2bf(f0.y); a8[2] = f2bf(f0.z); a8[3] = f2bf(f0.w);
        a8[4] = f2bf(f1.x); a8[5] = f2bf(f1.y); a8[6] = f2bf(f1.z); a8[7] = f2bf(f1.w);
        *(u16x8*)&As[row * 136 + kg * 8] = a8;
    }
    __syncthreads();

    int lane = t & 63;
    int wave = t >> 6;
    int wm2 = wave >> 1, wn2 = wave & 1;        // rows half / cols half
    int lr = lane & 15, quad = lane >> 4;

    #pragma unroll
    for (int mat = 0; mat < 4; ++mat) {
        const unsigned short* wm_ = wt + mat * 16384;
        const float* bias = (mat == 0) ? bq : (mat == 1) ? bk : (mat == 2) ? bv : bs;

        // preload all B fragments for this mat (16 dwordx4 loads in flight)
        bf16x8 bfr[4][4];
        #pragma unroll
        for (int ks = 0; ks < 4; ++ks)
            #pragma unroll
            for (int tn = 0; tn < 4; ++tn)
                bfr[ks][tn] = *(const bf16x8*)(wm_ + (wn2 * 64 + tn * 16 + lr) * 128
                                                    + ks * 32 + quad * 8);

        f32x4 acc[2][4];
        #pragma unroll
        for (int a = 0; a < 2; ++a)
            #pragma unroll
            for (int b = 0; b < 4; ++b)
                acc[a][b] = (f32x4){0.f, 0.f, 0.f, 0.f};

        #pragma unroll
        for (int ks = 0; ks < 4; ++ks) {
            bf16x8 af[2];
            #pragma unroll
            for (int tm = 0; tm < 2; ++tm)
                af[tm] = *(const bf16x8*)&As[(wm2 * 32 + tm * 16 + lr) * 136
                                             + ks * 32 + quad * 8];
            #pragma unroll
            for (int tm = 0; tm < 2; ++tm)
                #pragma unroll
                for (int tn = 0; tn < 4; ++tn)
                    acc[tm][tn] = __builtin_amdgcn_mfma_f32_16x16x32_bf16(
                        af[tm], bfr[ks][tn], acc[tm][tn], 0, 0, 0);
        }

        // C/D layout: col = lane&15, row = quad*4 + reg
        if (mat == 0 || mat == 3) {
            float* outp = (mat == 0) ? q : s;
            #pragma unroll
            for (int tn = 0; tn < 4; ++tn) {
                int col = wn2 * 64 + tn * 16 + lr;
                float bv_ = bias[col];
                #pragma unroll
                for (int tm = 0; tm < 2; ++tm) {
                    int nb = row0 + wm2 * 32 + tm * 16 + quad * 4;
                    #pragma unroll
                    for (int r = 0; r < 4; ++r) {
                        int node = nb + r;
                        if (node < NN)
                            outp[(size_t)node * DD + col] = acc[tm][tn][r] + bv_;
                    }
                }
            }
        } else {
            unsigned short* outp = (mat == 1) ? kb16 : vb16;
            #pragma unroll
            for (int tn = 0; tn < 4; ++tn) {
                int col = wn2 * 64 + tn * 16 + lr;
                float bv_ = bias[col];
                #pragma unroll
                for (int tm = 0; tm < 2; ++tm) {
                    int nb = row0 + wm2 * 32 + tm * 16 + quad * 4;
                    #pragma unroll
                    for (int r = 0; r < 4; ++r) {
                        int node = nb + r;
                        if (node < NN)
                            outp[(size_t)node * DD + col] = f2bf(acc[tm][tn][r] + bv_);
                    }
                }
            }
        }
    }
}

// ---------------- attention: 4 edges/wave via 16-lane subgroups ----------------

__global__ __launch_bounds__(256) void attn_kernel(
    const float* __restrict__ q, const unsigned short* __restrict__ kb16,
    const unsigned short* __restrict__ vb16, const float* __restrict__ s,
    const int* __restrict__ indptr, const int* __restrict__ esrc,
    float* __restrict__ hout, int n) {
    int node = (int)((blockIdx.x * blockDim.x + threadIdx.x) >> 6);
    int lane = threadIdx.x & 63;
    if (node >= n) return;
    int g = lane >> 4, j = lane & 15;

    const float* qp = q + (size_t)node * DD + j * 8;
    float4 q0 = *(const float4*)qp;
    float4 q1 = *(const float4*)(qp + 4);

    int beg = indptr[node], end = indptr[node + 1];

    float m = -3.0e38f, den = 0.f;
    float acc[8];
    #pragma unroll
    for (int c = 0; c < 8; ++c) acc[c] = 0.f;

    for (int e = beg + g; e < end; e += 4) {
        int sidx = esrc[e];
        u16x8 k8 = *(const u16x8*)(kb16 + (size_t)sidx * DD + j * 8);
        u16x8 v8 = *(const u16x8*)(vb16 + (size_t)sidx * DD + j * 8);
        float p;
        p  = q0.x * bf2f(k8[0]);
        p  = fmaf(q0.y, bf2f(k8[1]), p);
        p  = fmaf(q0.z, bf2f(k8[2]), p);
        p  = fmaf(q0.w, bf2f(k8[3]), p);
        p  = fmaf(q1.x, bf2f(k8[4]), p);
        p  = fmaf(q1.y, bf2f(k8[5]), p);
        p  = fmaf(q1.z, bf2f(k8[6]), p);
        p  = fmaf(q1.w, bf2f(k8[7]), p);
        p += __shfl_xor(p, 8);
        p += __shfl_xor(p, 4);
        p += __shfl_xor(p, 2);
        p += __shfl_xor(p, 1);
        float score = p * 0.088388347648318447f;   // 1/sqrt(128)
        float mn = fmaxf(m, score);
        float scale = __expf(m - mn);
        float pe = __expf(score - mn);
        den = den * scale + pe;
        #pragma unroll
        for (int c = 0; c < 8; ++c)
            acc[c] = fmaf(acc[c], scale, pe * bf2f(v8[c]));
        m = mn;
    }

    float mo = __shfl_xor(m, 16);
    float m2 = fmaxf(m, mo);
    mo = __shfl_xor(m2, 32);
    float mf = fmaxf(m2, mo);
    float sc = __expf(m - mf);
    den *= sc;
    den += __shfl_xor(den, 16);
    den += __shfl_xor(den, 32);
    #pragma unroll
    for (int c = 0; c < 8; ++c) {
        float a = acc[c] * sc;
        a += __shfl_xor(a, 16);
        a += __shfl_xor(a, 32);
        acc[c] = a;
    }
    float inv = den > 0.f ? 1.0f / den : 0.f;
    if (g == 0) {
        const float* sp = s + (size_t)node * DD + j * 8;
        float4 s0 = *(const float4*)sp;
        float4 s1 = *(const float4*)(sp + 4);
        float4 o0, o1;
        o0.x = fmaxf(fmaf(acc[0], inv, s0.x), 0.f);
        o0.y = fmaxf(fmaf(acc[1], inv, s0.y), 0.f);
        o0.z = fmaxf(fmaf(acc[2], inv, s0.z), 0.f);
        o0.w = fmaxf(fmaf(acc[3], inv, s0.w), 0.f);
        o1.x = fmaxf(fmaf(acc[4], inv, s1.x), 0.f);
        o1.y = fmaxf(fmaf(acc[5], inv, s1.y), 0.f);
        o1.z = fmaxf(fmaf(acc[6], inv, s1.z), 0.f);
        o1.w = fmaxf(fmaf(acc[7], inv, s1.w), 0.f);
        float* op = hout + (size_t)node * DD + j * 8;
        *(float4*)op = o0;
        *(float4*)(op + 4) = o1;
    }
}

// ---------------- global mean pool: segmented running sum ----------------

__global__ __launch_bounds__(128) void pool_kernel(const float* __restrict__ h,
                                                   const int* __restrict__ batch,
                                                   float* __restrict__ gsum,
                                                   float* __restrict__ gcnt, int n) {
    __shared__ int bsh[PCHUNK];
    int t = threadIdx.x;
    int node0 = blockIdx.x * PCHUNK;
    int nnodes = min(PCHUNK, n - node0);
    if (t < nnodes) bsh[t] = batch[node0 + t];
    __syncthreads();

    int cur = bsh[0];
    float acc = 0.f;
    int cnt = 0;
    int j = 0;
    for (; j + 4 <= nnodes; j += 4) {
        float v0 = h[(size_t)(node0 + j + 0) * DD + t];
        float v1 = h[(size_t)(node0 + j + 1) * DD + t];
        float v2 = h[(size_t)(node0 + j + 2) * DD + t];
        float v3 = h[(size_t)(node0 + j + 3) * DD + t];
        int g0 = bsh[j + 0], g1 = bsh[j + 1], g2 = bsh[j + 2], g3 = bsh[j + 3];
        #pragma unroll
        for (int u = 0; u < 4; ++u) {
            int g = (u == 0) ? g0 : (u == 1) ? g1 : (u == 2) ? g2 : g3;
            float val = (u == 0) ? v0 : (u == 1) ? v1 : (u == 2) ? v2 : v3;
            if (g != cur) {
                atomicAdd(&gsum[cur * DD + t], acc);
                if (t == 0) atomicAdd(&gcnt[cur], (float)cnt);
                acc = 0.f; cnt = 0; cur = g;
            }
            acc += val; ++cnt;
        }
    }
    for (; j < nnodes; ++j) {
        int g = bsh[j];
        float val = h[(size_t)(node0 + j) * DD + t];
        if (g != cur) {
            atomicAdd(&gsum[cur * DD + t], acc);
            if (t == 0) atomicAdd(&gcnt[cur], (float)cnt);
            acc = 0.f; cnt = 0; cur = g;
        }
        acc += val; ++cnt;
    }
    if (cnt > 0) {
        atomicAdd(&gsum[cur * DD + t], acc);
        if (t == 0) atomicAdd(&gcnt[cur], (float)cnt);
    }
}

// ---------------- FC + log_softmax ----------------

__global__ __launch_bounds__(64) void head_kernel(
    const float* __restrict__ gsum, const float* __restrict__ gcnt,
    const float* __restrict__ wfc, const float* __restrict__ bfc,
    float* __restrict__ out) {
    int g = blockIdx.x;
    int lane = threadIdx.x;
    float cnt = fmaxf(gcnt[g], 1.0f);
    float inv = 1.0f / cnt;
    float p0 = gsum[g * DD + lane] * inv;
    float p1 = gsum[g * DD + lane + 64] * inv;
    __shared__ float logits[NCLS];
    for (int c = 0; c < NCLS; ++c) {
        float partial = p0 * wfc[lane * NCLS + c] + p1 * wfc[(lane + 64) * NCLS + c];
        partial += __shfl_xor(partial, 32);
        partial += __shfl_xor(partial, 16);
        partial += __shfl_xor(partial, 8);
        partial += __shfl_xor(partial, 4);
        partial += __shfl_xor(partial, 2);
        partial += __shfl_xor(partial, 1);
        if (lane == 0) logits[c] = partial + bfc[c];
    }
    __syncthreads();
    if (lane == 0) {
        float mx = logits[0];
        for (int c = 1; c < NCLS; ++c) mx = fmaxf(mx, logits[c]);
        float sum = 0.f;
        for (int c = 0; c < NCLS; ++c) sum += expf(logits[c] - mx);
        float lse = mx + logf(sum);
        for (int c = 0; c < NCLS; ++c) out[g * NCLS + c] = logits[c] - lse;
    }
}

// ---------------- launch ----------------

extern "C" void kernel_launch(void* const* d_in, const int* in_sizes, int n_in,
                              void* d_out, int out_size, void* d_ws, size_t ws_size,
                              hipStream_t stream) {
    const float* x     = (const float*)d_in[0];
    const int*   ei    = (const int*)d_in[1];
    const int*   batch = (const int*)d_in[2];
    const float* Wq = (const float*)d_in[3];
    const float* bq = (const float*)d_in[4];
    const float* Wk = (const float*)d_in[5];
    const float* bk = (const float*)d_in[6];
    const float* Wv = (const float*)d_in[7];
    const float* bv = (const float*)d_in[8];
    const float* Ws = (const float*)d_in[9];
    const float* bs = (const float*)d_in[10];
    const float* Wfc = (const float*)d_in[11];
    const float* bfc = (const float*)d_in[12];
    float* out = (float*)d_out;

    const size_t ND = (size_t)NN * DD;
    float* hbuf = (float*)d_ws;
    float* qb = hbuf + ND;
    float* sb = qb + ND;
    unsigned short* kb16 = (unsigned short*)(sb + ND);
    unsigned short* vb16 = kb16 + ND;
    unsigned short* wt = vb16 + ND;                 // [2][4][128][128] bf16, 16B-aligned
    int* cnt    = (int*)(wt + 2 * 4 * 16384);
    int* indptr = cnt + NN;
    int* cursor = indptr + NN + 1;
    int* esrc   = cursor + NN;
    int* lexcl  = esrc + EE;
    int* csum   = lexcl + NN;
    float* gsum = (float*)(csum + NCHUNK);
    float* gcnt = gsum + GG * DD;

    const int* src = ei;
    const int* dst = ei + EE;

    hipMemsetAsync(cnt, 0, NN * sizeof(int), stream);
    hipMemsetAsync(gsum, 0, (GG * DD + GG) * sizeof(float), stream);

    hist_kernel<<<(EE + 255) / 256, 256, 0, stream>>>(dst, cnt, EE);
    scan1_kernel<<<NCHUNK, 1024, 0, stream>>>(cnt, lexcl, csum, NN);
    scan2_kernel<<<1, 64, 0, stream>>>(csum, NCHUNK);
    scan3_kernel<<<NCHUNK, 1024, 0, stream>>>(lexcl, csum, indptr, cursor, NN, EE);
    fill_kernel<<<(EE + 255) / 256, 256, 0, stream>>>(src, dst, cursor, esrc, EE);
    wt_kernel<<<512, 256, 0, stream>>>(Wq, Wk, Wv, Ws, wt);

    for (int l = 0; l < 2; ++l) {
        const float* hin = (l == 0) ? x : hbuf;
        size_t bo = (size_t)l * DD;
        gemm_mfma<<<(NN + 63) / 64, 256, 0, stream>>>(
            hin, wt + (size_t)l * 4 * 16384,
            bq + bo, bk + bo, bv + bo, bs + bo,
            qb, kb16, vb16, sb);
        attn_kernel<<<(NN + 3) / 4, 256, 0, stream>>>(
            qb, kb16, vb16, sb, indptr, esrc, hbuf, NN);
    }

    pool_kernel<<<(NN + PCHUNK - 1) / PCHUNK, 128, 0, stream>>>(hbuf, batch, gsum, gcnt, NN);
    head_kernel<<<GG, 64, 0, stream>>>(gsum, gcnt, Wfc, bfc, out);
}